// Round 4
// baseline (1219.453 us; speedup 1.0000x reference)
//
#include <hip/hip_runtime.h>

typedef __bf16 bf16x8 __attribute__((ext_vector_type(8)));
typedef float  f32x4  __attribute__((ext_vector_type(4)));
union BF8 { unsigned short s[8]; bf16x8 v; };

__device__ __forceinline__ unsigned short f2bf(float x){
  unsigned u = __float_as_uint(x);
  u += 0x7fffu + ((u >> 16) & 1u);      // round-to-nearest-even
  return (unsigned short)(u >> 16);
}
__device__ __forceinline__ float bf2f(unsigned short s){ return __uint_as_float(((unsigned)s) << 16); }
__device__ __forceinline__ float sigm(float x){ return 1.0f/(1.0f + __expf(-x)); }
__device__ __forceinline__ float tanh_fast(float x){ return 1.0f - 2.0f/(__expf(2.0f*x)+1.0f); }

// ---------------- prep: W -> bf16 pre-swizzled (chunk-of-8 ^ (row&7)) ----------------
__global__ void k_prep(const float* __restrict__ Wihf, const float* __restrict__ Whhf,
                       const float* __restrict__ linw,
                       unsigned short* __restrict__ Wih_sw, unsigned short* __restrict__ Whh_sw,
                       unsigned short* __restrict__ lin_sw)
{
  int tid = blockIdx.x*256 + threadIdx.x;
  if (tid < 49152){
    int row = tid >> 7, col = tid & 127;
    Wih_sw[row*128 + (((col>>3) ^ (row&7))<<3) + (col&7)] = f2bf(Wihf[tid]);
  } else if (tid < 98304){
    int i = tid - 49152; int row = i >> 7, col = i & 127;
    Whh_sw[row*128 + (((col>>3) ^ (row&7))<<3) + (col&7)] = f2bf(Whhf[i]);
  } else if (tid < 114688){
    int i = tid - 98304; int row = i >> 7, col = i & 127;
    lin_sw[row*128 + (((col>>3) ^ (row&7))<<3) + (col&7)] = f2bf(linw[i]);
  }
}

// ---------------- edge index dtype sniff ----------------
__global__ void k_detect(const int* __restrict__ ei, unsigned* __restrict__ flag){
  int v = ei[2*threadIdx.x + 1];
  unsigned long long b = __ballot(v == 0);
  if (threadIdx.x == 0) flag[0] = (b == ~0ULL) ? 1u : 0u;
}

__global__ void k_zero(int* __restrict__ deg, int N){
  int tid = blockIdx.x*256 + threadIdx.x;
  if (tid < N) deg[tid] = 0;
}

// normalize edges + histogram destinations
__global__ void k_norm(const void* __restrict__ ei, const unsigned* __restrict__ flag,
                       int* __restrict__ src, int* __restrict__ dst, int* __restrict__ deg, int E){
  int e = blockIdx.x*256 + threadIdx.x;
  if (e >= E) return;
  int s, d;
  if (flag[0]){
    const long long* p = (const long long*)ei;
    s = (int)p[e]; d = (int)p[(size_t)E + e];
  } else {
    const int* p = (const int*)ei;
    s = p[e]; d = p[E + e];
  }
  src[e] = s; dst[e] = d;
  atomicAdd(&deg[d], 1);
}

// single-wave exclusive scan over deg -> off[0..N], zero cursors
__global__ void k_scan(const int* __restrict__ deg, int* __restrict__ off,
                       int* __restrict__ cur, int N){
  int lane = threadIdx.x;
  int carry = 0;
  for (int base = 0; base < N; base += 64){
    int i = base + lane;
    int v = (i < N) ? deg[i] : 0;
    int inc = v;
    #pragma unroll
    for (int d2 = 1; d2 < 64; d2 <<= 1){
      int u = __shfl_up(inc, d2);
      if (lane >= d2) inc += u;
    }
    if (i < N){ off[i] = carry + inc - v; cur[i] = 0; }
    carry += __shfl(inc, 63);
  }
  if (lane == 0) off[N] = carry;
}

// scatter edge sources into CSR
__global__ void k_scatter(const int* __restrict__ src, const int* __restrict__ dst,
                          const int* __restrict__ off, int* __restrict__ cur,
                          int* __restrict__ eid, int E){
  int e = blockIdx.x*256 + threadIdx.x;
  if (e >= E) return;
  int d = dst[e];
  int p = off[d] + atomicAdd(&cur[d], 1);
  eid[p] = src[e];
}

// ---------------- phase A: gi = x @ W_ih^T + biases, linear [tile][t] layout ----------------
__global__ __launch_bounds__(512) void k_phA(
    const float* __restrict__ seq, const unsigned short* __restrict__ Wih_sw,
    const float* __restrict__ bih, const float* __restrict__ bhh,
    unsigned short* __restrict__ gi, int nT, int N, int tch, int chunk)
{
  __shared__ unsigned short Wlds[49152];
  const int tid = threadIdx.x;
  for (int i = tid; i < 6144; i += 512)
    ((uint4*)Wlds)[i] = ((const uint4*)Wih_sw)[i];
  __syncthreads();
  const int lane = tid & 63, wloc = tid >> 6;
  const int col4 = lane & 15, grp = lane >> 4;

  float bias[24];
  #pragma unroll
  for (int g=0; g<24; ++g){
    int ch = g*16 + col4;
    bias[g] = bih[ch] + (g < 16 ? bhh[ch] : 0.0f);   // fold b_hh into r,z; NOT n
  }

  const int hsteps = tch >> 1;           // timesteps per half-job
  const int nJobs = nT * 2;

  for (int job = blockIdx.x*8 + wloc; job < nJobs; job += 2048){
    const int tile = job >> 1;
    const int th   = job & 1;
    int nrow = tile*16 + col4; if (nrow >= N) nrow = N-1;
    const float* rowp = seq + ((size_t)nrow*16 + chunk*tch + th*hsteps)*128 + grp*8;

    f32x4 Alo[4], Ahi[4], Blo[4], Bhi[4];
    #pragma unroll
    for (int kt=0; kt<4; ++kt){
      Alo[kt] = *(const f32x4*)(rowp + kt*32);
      Ahi[kt] = *(const f32x4*)(rowp + kt*32 + 4);
    }

    auto body = [&](f32x4* cLo, f32x4* cHi, f32x4* nLo, f32x4* nHi, int i){
      // issue next timestep's loads first (hidden under MFMA)
      if (i + 1 < hsteps){
        const float* np = rowp + (size_t)(i+1)*128;
        #pragma unroll
        for (int kt=0; kt<4; ++kt){
          nLo[kt] = *(const f32x4*)(np + kt*32);
          nHi[kt] = *(const f32x4*)(np + kt*32 + 4);
        }
      }
      bf16x8 xa[4];
      #pragma unroll
      for (int kt=0; kt<4; ++kt){
        BF8 u;
        #pragma unroll
        for (int j=0;j<4;++j){ u.s[j]=f2bf(cLo[kt][j]); u.s[4+j]=f2bf(cHi[kt][j]); }
        xa[kt] = u.v;
      }
      f32x4 acc[24];
      #pragma unroll
      for (int g=0; g<24; ++g) acc[g] = (f32x4){bias[g],bias[g],bias[g],bias[g]};
      #pragma unroll
      for (int kt=0; kt<4; ++kt){
        #pragma unroll
        for (int g=0; g<24; ++g){
          int row = g*16 + col4;
          const bf16x8 b = *(const bf16x8*)(Wlds + row*128 + (((kt*4+grp) ^ (row&7))<<3));
          acc[g] = __builtin_amdgcn_mfma_f32_16x16x32_bf16(xa[kt], b, acc[g], 0,0,0);
        }
      }
      // store 96 bf16/lane into gi[tile][tloc], 12KB sequential per step
      const int tloc = th*hsteps + i;
      bf16x8* dstp = (bf16x8*)gi + ((size_t)tile*tch + tloc)*768;
      #pragma unroll
      for (int j=0; j<12; ++j){
        BF8 u;
        #pragma unroll
        for (int e=0; e<8; ++e){
          int idx = j*8+e;
          u.s[e] = f2bf(acc[idx>>2][idx&3]);
        }
        __builtin_nontemporal_store(u.v, &dstp[j*64 + lane]);
      }
    };

    for (int i = 0; i < hsteps; i += 2){
      body(Alo, Ahi, Blo, Bhi, i);
      if (i + 1 < hsteps) body(Blo, Bhi, Alo, Ahi, i+1);
    }
  }
}

// ---------------- phase B: sequential GRU steps, W_hh in LDS, h in registers ----------------
__global__ __launch_bounds__(512) void k_phB(
    const unsigned short* __restrict__ Whh_sw, const float* __restrict__ bhh,
    const unsigned short* __restrict__ gi, float* __restrict__ hstate,
    float* __restrict__ hout, int nT, int N, int tch, int chunk, int last)
{
  __shared__ unsigned short Wlds[49152];
  __shared__ unsigned short hbuf[8][2048];
  const int tid = threadIdx.x;
  for (int i = tid; i < 6144; i += 512)
    ((uint4*)Wlds)[i] = ((const uint4*)Whh_sw)[i];
  __syncthreads();
  const int lane = tid & 63, wloc = tid >> 6;
  const int col4 = lane & 15, grp = lane >> 4;
  unsigned short* myh = hbuf[wloc];

  float bn[8];
  #pragma unroll
  for (int ct=0; ct<8; ++ct) bn[ct] = bhh[256 + ct*16 + col4];

  for (int tile = blockIdx.x*8 + wloc; tile < nT; tile += 2048){
    float h[8][4];
    if (chunk == 0){
      #pragma unroll
      for (int ct=0;ct<8;++ct)
        #pragma unroll
        for (int q=0;q<4;++q) h[ct][q] = 0.0f;
    } else {
      const float* hp = hstate + ((size_t)tile*64 + lane)*32;
      #pragma unroll
      for (int ct=0;ct<8;++ct)
        #pragma unroll
        for (int q=0;q<4;++q) h[ct][q] = hp[ct*4+q];
      #pragma unroll
      for (int ct=0;ct<8;++ct)
        #pragma unroll
        for (int q=0;q<4;++q){
          int m = grp*4 + q, c = ct*16 + col4;
          int c2 = (c>>3) ^ (m&7);
          myh[m*128 + c2*8 + (c&7)] = f2bf(h[ct][q]);
        }
    }
    const bf16x8* gbase = (const bf16x8*)gi + (size_t)tile*tch*768;
    BF8 gA[12], gB[12];
    #pragma unroll
    for (int j=0;j<12;++j) gA[j].v = __builtin_nontemporal_load(&gbase[(size_t)j*64 + lane]);

    auto gstep = [&](int tloc, BF8* gin, BF8* gpre){
      if (tloc + 1 < tch){
        const bf16x8* gp2 = gbase + (size_t)(tloc+1)*768;
        #pragma unroll
        for (int j=0;j<12;++j) gpre[j].v = __builtin_nontemporal_load(&gp2[(size_t)j*64 + lane]);
      }
      bf16x8 ha[4];
      if (chunk == 0 && tloc == 0){
        BF8 uz;
        #pragma unroll
        for (int j=0;j<8;++j) uz.s[j]=0;
        #pragma unroll
        for (int kt=0;kt<4;++kt) ha[kt]=uz.v;
      } else {
        #pragma unroll
        for (int kt=0;kt<4;++kt){
          int ck = (kt*4+grp) ^ (col4&7);
          ha[kt] = *(const bf16x8*)(myh + col4*128 + ck*8);
        }
      }
      #pragma unroll
      for (int hf=0; hf<2; ++hf){
        f32x4 a_r[4], a_z[4], a_n[4];
        #pragma unroll
        for (int j=0;j<4;++j){
          a_r[j] = (f32x4)0.0f; a_z[j] = (f32x4)0.0f;
          float b = bn[hf*4+j];
          a_n[j] = (f32x4){b,b,b,b};
        }
        #pragma unroll
        for (int kt=0;kt<4;++kt){
          #pragma unroll
          for (int j=0;j<4;++j){
            int ct = hf*4+j;
            int rr = (     ct)*16 + col4;
            int rz = ( 8 + ct)*16 + col4;
            int rn = (16 + ct)*16 + col4;
            const bf16x8 br  = *(const bf16x8*)(Wlds + rr*128 + (((kt*4+grp)^(rr&7))<<3));
            const bf16x8 bz  = *(const bf16x8*)(Wlds + rz*128 + (((kt*4+grp)^(rz&7))<<3));
            const bf16x8 bnn = *(const bf16x8*)(Wlds + rn*128 + (((kt*4+grp)^(rn&7))<<3));
            a_r[j] = __builtin_amdgcn_mfma_f32_16x16x32_bf16(ha[kt], br,  a_r[j], 0,0,0);
            a_z[j] = __builtin_amdgcn_mfma_f32_16x16x32_bf16(ha[kt], bz,  a_z[j], 0,0,0);
            a_n[j] = __builtin_amdgcn_mfma_f32_16x16x32_bf16(ha[kt], bnn, a_n[j], 0,0,0);
          }
        }
        #pragma unroll
        for (int j=0;j<4;++j){
          int ct = hf*4+j;
          #pragma unroll
          for (int q=0;q<4;++q){
            int ir = (     ct)*4+q;
            int iz = ( 8 + ct)*4+q;
            int in = (16 + ct)*4+q;
            float gr = a_r[j][q] + bf2f(gin[ir>>3].s[ir&7]);
            float gz = a_z[j][q] + bf2f(gin[iz>>3].s[iz&7]);
            float gn = bf2f(gin[in>>3].s[in&7]);
            float r = sigm(gr), z = sigm(gz);
            float nn = tanh_fast(gn + r * a_n[j][q]);
            float hv = h[ct][q];
            hv = nn + z*(hv - nn);
            h[ct][q] = hv;
            int m = grp*4 + q, c = ct*16 + col4;
            int c2 = (c>>3) ^ (m&7);
            myh[m*128 + c2*8 + (c&7)] = f2bf(hv);
          }
        }
      }
    };

    for (int tloc = 0; tloc < tch; tloc += 2){
      gstep(tloc, gA, gB);
      if (tloc + 1 < tch) gstep(tloc+1, gB, gA);
    }

    if (last){
      #pragma unroll
      for (int ct=0;ct<8;++ct)
        #pragma unroll
        for (int q=0;q<4;++q){
          int n = tile*16 + grp*4 + q;
          if (n < N) hout[(size_t)n*128 + ct*16 + col4] = h[ct][q];
        }
    } else {
      float* hp = hstate + ((size_t)tile*64 + lane)*32;
      #pragma unroll
      for (int ct=0;ct<8;++ct)
        #pragma unroll
        for (int q=0;q<4;++q) hp[ct*4+q] = h[ct][q];
    }
  }
}

// ---------------- GAT linear (MFMA) + fused attention scalars; x stored bf16 ----------------
__global__ __launch_bounds__(256) void k_gat1(
    const float* __restrict__ hsrc, const unsigned short* __restrict__ lin_sw,
    const float* __restrict__ att_s, const float* __restrict__ att_d,
    unsigned short* __restrict__ xbf, float* __restrict__ a_s, float* __restrict__ a_d,
    int N, int nT)
{
  __shared__ unsigned short Llds[16384];
  const int tid = threadIdx.x;
  for (int i = tid; i < 2048; i += 256)
    ((uint4*)Llds)[i] = ((const uint4*)lin_sw)[i];
  __syncthreads();
  const int lane = tid & 63, wloc = tid >> 6;
  const int col4 = lane & 15, grp = lane >> 4;
  const int tile = blockIdx.x*4 + wloc;
  if (tile >= nT) return;
  float ats[8], atd[8];
  #pragma unroll
  for (int ct=0;ct<8;++ct){ ats[ct] = att_s[ct*16+col4]; atd[ct] = att_d[ct*16+col4]; }
  int nrow = tile*16 + col4; if (nrow >= N) nrow = N-1;
  const float* xr = hsrc + (size_t)nrow*128 + grp*8;
  bf16x8 xa[4];
  #pragma unroll
  for (int kt=0;kt<4;++kt){
    f32x4 lo = *(const f32x4*)(xr + kt*32);
    f32x4 hi = *(const f32x4*)(xr + kt*32 + 4);
    BF8 u;
    #pragma unroll
    for (int j=0;j<4;++j){ u.s[j]=f2bf(lo[j]); u.s[4+j]=f2bf(hi[j]); }
    xa[kt] = u.v;
  }
  f32x4 acc[8];
  #pragma unroll
  for (int ct=0;ct<8;++ct) acc[ct] = (f32x4)0.0f;
  #pragma unroll
  for (int kt=0;kt<4;++kt){
    #pragma unroll
    for (int ct=0;ct<8;++ct){
      int row = ct*16+col4;
      const bf16x8 b = *(const bf16x8*)(Llds + row*128 + (((kt*4+grp)^(row&7))<<3));
      acc[ct] = __builtin_amdgcn_mfma_f32_16x16x32_bf16(xa[kt], b, acc[ct], 0,0,0);
    }
  }
  float ss[4] = {0,0,0,0}, dd[4] = {0,0,0,0};
  #pragma unroll
  for (int ct=0;ct<8;++ct)
    #pragma unroll
    for (int q=0;q<4;++q){
      float xv = acc[ct][q];
      int n = tile*16 + grp*4 + q;
      if (n < N) xbf[(size_t)n*128 + ct*16 + col4] = f2bf(xv);
      ss[q] += xv * ats[ct];
      dd[q] += xv * atd[ct];
    }
  #pragma unroll
  for (int m=1; m<16; m<<=1){
    #pragma unroll
    for (int q=0;q<4;++q){
      ss[q] += __shfl_xor(ss[q], m);
      dd[q] += __shfl_xor(dd[q], m);
    }
  }
  if (col4 == 0){
    #pragma unroll
    for (int q=0;q<4;++q){
      int n = tile*16 + grp*4 + q;
      if (n < N){ a_s[n] = ss[q]; a_d[n] = dd[q]; }
    }
  }
}

// ---------------- CSR aggregation: one wave per destination node, no atomics ----------------
__global__ __launch_bounds__(256) void k_agg2(
    const int* __restrict__ off, const int* __restrict__ eid,
    const float* __restrict__ a_s, const float* __restrict__ a_d,
    const unsigned short* __restrict__ xbf, const float* __restrict__ bias,
    float* __restrict__ out2, int N)
{
  int d = blockIdx.x*4 + (threadIdx.x >> 6);
  if (d >= N) return;
  const int lane = threadIdx.x & 63;
  const unsigned* xw = (const unsigned*)xbf;   // 2 bf16 channels per uint
  const float ad_d = a_d[d];
  // self loop
  float a0 = a_s[d] + ad_d; a0 = a0 > 0.f ? a0 : 0.2f*a0;
  float w = __expf(a0);
  unsigned pv = xw[(size_t)d*64 + lane];
  float den  = w;
  float acc0 = w * bf2f((unsigned short)(pv & 0xffffu));
  float acc1 = w * bf2f((unsigned short)(pv >> 16));
  const int i1 = off[d+1];
  for (int i = off[d]; i < i1; ++i){
    int s = eid[i];
    float a = a_s[s] + ad_d; a = a > 0.f ? a : 0.2f*a;
    float ww = __expf(a);
    unsigned pp = xw[(size_t)s*64 + lane];
    den  += ww;
    acc0 += ww * bf2f((unsigned short)(pp & 0xffffu));
    acc1 += ww * bf2f((unsigned short)(pp >> 16));
  }
  float inv = 1.0f/den;
  float2 o;
  o.x = acc0*inv + bias[2*lane];
  o.y = acc1*inv + bias[2*lane+1];
  *(float2*)(out2 + (size_t)d*128 + 2*lane) = o;
}

extern "C" void kernel_launch(void* const* d_in, const int* in_sizes, int n_in,
                              void* d_out, int out_size, void* d_ws, size_t ws_size,
                              hipStream_t stream)
{
  const float* seq  = (const float*)d_in[0];
  const void*  ei   = d_in[1];
  const float* Wihf = (const float*)d_in[2];
  const float* Whhf = (const float*)d_in[3];
  const float* bih  = (const float*)d_in[4];
  const float* bhh  = (const float*)d_in[5];
  const float* linw = (const float*)d_in[6];
  const float* atts = (const float*)d_in[7];
  const float* attd = (const float*)d_in[8];
  const float* gbias= (const float*)d_in[9];

  const int N  = in_sizes[0] / (16*128);
  const int E  = in_sizes[1] / 2;
  const int nT = (N + 15) / 16;

  char* ws = (char*)d_ws;
  size_t off_b = 0;
  auto alloc = [&](size_t bytes) -> char* {
    char* p = ws + off_b;
    off_b = (off_b + bytes + 255) & ~(size_t)255;
    return p;
  };
  unsigned short* Wih_sw = (unsigned short*)alloc(98304);
  unsigned short* Whh_sw = (unsigned short*)alloc(98304);
  unsigned short* lin_sw = (unsigned short*)alloc(32768);
  unsigned short* xbf    = (unsigned short*)alloc((size_t)N*128*2);
  float*    a_s    = (float*)   alloc((size_t)N*4);
  float*    a_d    = (float*)   alloc((size_t)N*4);
  float*    hstate = (float*)   alloc((size_t)nT*16*128*4);
  unsigned* flag   = (unsigned*)alloc(64);
  int*      srcA   = (int*)     alloc((size_t)E*4);
  int*      dstA   = (int*)     alloc((size_t)E*4);
  int*      deg    = (int*)     alloc((size_t)N*4);
  int*      offs   = (int*)     alloc((size_t)(N+1)*4);
  int*      cur    = (int*)     alloc((size_t)N*4);
  int*      eid    = (int*)     alloc((size_t)E*4);

  // choose largest timestep-chunk whose gi slab fits remaining workspace
  const size_t perT = (size_t)nT * 12288;   // bytes of gi per timestep
  int tch = 16;
  while (tch > 2 && off_b + (size_t)tch*perT > ws_size) tch >>= 1;
  unsigned short* gi = (unsigned short*)alloc((size_t)tch*perT);
  const int chunks = 16 / tch;

  float* hout = (float*)d_out;
  float* out2 = hout + (size_t)N*128;

  k_prep   <<<448, 256, 0, stream>>>(Wihf, Whhf, linw, Wih_sw, Whh_sw, lin_sw);
  k_detect <<<1, 64, 0, stream>>>((const int*)ei, flag);
  k_zero   <<<(N + 255)/256, 256, 0, stream>>>(deg, N);
  k_norm   <<<(E + 255)/256, 256, 0, stream>>>(ei, flag, srcA, dstA, deg, E);
  k_scan   <<<1, 64, 0, stream>>>(deg, offs, cur, N);
  k_scatter<<<(E + 255)/256, 256, 0, stream>>>(srcA, dstA, offs, cur, eid, E);

  for (int c = 0; c < chunks; ++c){
    k_phA<<<256, 512, 0, stream>>>(seq, Wih_sw, bih, bhh, gi, nT, N, tch, c);
    k_phB<<<256, 512, 0, stream>>>(Whh_sw, bhh, gi, hstate, hout, nT, N, tch, c, c == chunks-1);
  }

  k_gat1<<<(nT + 3)/4, 256, 0, stream>>>(hout, lin_sw, atts, attd, xbf, a_s, a_d, N, nT);
  k_agg2<<<(N + 3)/4, 256, 0, stream>>>(offs, eid, a_s, a_d, xbf, gbias, out2, N);
}

// Round 5
// 1152.807 us; speedup vs baseline: 1.0578x; 1.0578x over previous
//
#include <hip/hip_runtime.h>

typedef __bf16 bf16x8 __attribute__((ext_vector_type(8)));
typedef float  f32x4  __attribute__((ext_vector_type(4)));
union BF8 { unsigned short s[8]; bf16x8 v; };

__device__ __forceinline__ unsigned short f2bf(float x){
  unsigned u = __float_as_uint(x);
  u += 0x7fffu + ((u >> 16) & 1u);      // round-to-nearest-even
  return (unsigned short)(u >> 16);
}
__device__ __forceinline__ float bf2f(unsigned short s){ return __uint_as_float(((unsigned)s) << 16); }
__device__ __forceinline__ float sigm(float x){ return 1.0f/(1.0f + __expf(-x)); }
__device__ __forceinline__ float tanh_fast(float x){ return 1.0f - 2.0f/(__expf(2.0f*x)+1.0f); }

// ---------------- prep: split W into bf16 pre-swizzled slabs ----------------
__global__ void k_prep(const float* __restrict__ Wihf, const float* __restrict__ Whhf,
                       const float* __restrict__ linw,
                       unsigned short* __restrict__ Wihrz, unsigned short* __restrict__ Wihn,
                       unsigned short* __restrict__ Whh_sw, unsigned short* __restrict__ lin_sw)
{
  int tid = blockIdx.x*256 + threadIdx.x;
  if (tid < 32768){                       // Wih rows 0..255 (r,z gates)
    int row = tid >> 7, col = tid & 127;
    Wihrz[row*128 + (((col>>3) ^ (row&7))<<3) + (col&7)] = f2bf(Wihf[tid]);
  } else if (tid < 49152){                // Wih rows 256..383 (n gate), local row 0..127
    int i = tid - 32768; int row = i >> 7, col = i & 127;
    Wihn[row*128 + (((col>>3) ^ (row&7))<<3) + (col&7)] = f2bf(Wihf[tid]);
  } else if (tid < 98304){
    int i = tid - 49152; int row = i >> 7, col = i & 127;
    Whh_sw[row*128 + (((col>>3) ^ (row&7))<<3) + (col&7)] = f2bf(Whhf[i]);
  } else if (tid < 114688){
    int i = tid - 98304; int row = i >> 7, col = i & 127;
    lin_sw[row*128 + (((col>>3) ^ (row&7))<<3) + (col&7)] = f2bf(linw[i]);
  }
}

// ---------------- edge index dtype sniff ----------------
__global__ void k_detect(const int* __restrict__ ei, unsigned* __restrict__ flag){
  int v = ei[2*threadIdx.x + 1];
  unsigned long long b = __ballot(v == 0);
  if (threadIdx.x == 0) flag[0] = (b == ~0ULL) ? 1u : 0u;
}

__global__ void k_zero(int* __restrict__ deg, int N){
  int tid = blockIdx.x*256 + threadIdx.x;
  if (tid < N) deg[tid] = 0;
}

__global__ void k_norm(const void* __restrict__ ei, const unsigned* __restrict__ flag,
                       int* __restrict__ src, int* __restrict__ dst, int* __restrict__ deg, int E){
  int e = blockIdx.x*256 + threadIdx.x;
  if (e >= E) return;
  int s, d;
  if (flag[0]){
    const long long* p = (const long long*)ei;
    s = (int)p[e]; d = (int)p[(size_t)E + e];
  } else {
    const int* p = (const int*)ei;
    s = p[e]; d = p[E + e];
  }
  src[e] = s; dst[e] = d;
  atomicAdd(&deg[d], 1);
}

__global__ void k_scan(const int* __restrict__ deg, int* __restrict__ off,
                       int* __restrict__ cur, int N){
  int lane = threadIdx.x;
  int carry = 0;
  for (int base = 0; base < N; base += 64){
    int i = base + lane;
    int v = (i < N) ? deg[i] : 0;
    int inc = v;
    #pragma unroll
    for (int d2 = 1; d2 < 64; d2 <<= 1){
      int u = __shfl_up(inc, d2);
      if (lane >= d2) inc += u;
    }
    if (i < N){ off[i] = carry + inc - v; cur[i] = 0; }
    carry += __shfl(inc, 63);
  }
  if (lane == 0) off[N] = carry;
}

__global__ void k_scatter(const int* __restrict__ src, const int* __restrict__ dst,
                          const int* __restrict__ off, int* __restrict__ cur,
                          int* __restrict__ eid, int E){
  int e = blockIdx.x*256 + threadIdx.x;
  if (e >= E) return;
  int d = dst[e];
  int p = off[d] + atomicAdd(&cur[d], 1);
  eid[p] = src[e];
}

// ---------------- phase A2: gi_rz = x @ Wih_rz^T + (bih+bhh)_rz ----------------
__global__ __launch_bounds__(512) void k_phA2(
    const float* __restrict__ seq, const unsigned short* __restrict__ Wihrz,
    const float* __restrict__ bih, const float* __restrict__ bhh,
    unsigned short* __restrict__ girz, int nT, int N)
{
  __shared__ unsigned short Wlds[32768];   // 256 x 128 bf16 = 64KB
  const int tid = threadIdx.x;
  for (int i = tid; i < 4096; i += 512)
    ((uint4*)Wlds)[i] = ((const uint4*)Wihrz)[i];
  __syncthreads();
  const int lane = tid & 63, wloc = tid >> 6;
  const int col4 = lane & 15, grp = lane >> 4;

  float bias[16];
  #pragma unroll
  for (int g=0; g<16; ++g){
    int c = g*16 + col4;                   // och 0..255 spans r,z
    bias[g] = bih[c] + bhh[c];
  }

  const int nJobs = nT * 2;
  for (int wid = blockIdx.x*8 + wloc; wid < nJobs; wid += 4096){
    const int tile = wid >> 1, th = wid & 1;
    int nrow = tile*16 + col4; if (nrow >= N) nrow = N-1;
    const float* rowp = seq + ((size_t)nrow*16 + th*8)*128 + grp*8;

    f32x4 Alo[4], Ahi[4], Blo[4], Bhi[4];
    #pragma unroll
    for (int kt=0; kt<4; ++kt){
      Alo[kt] = *(const f32x4*)(rowp + kt*32);
      Ahi[kt] = *(const f32x4*)(rowp + kt*32 + 4);
    }

    auto body = [&](f32x4* cLo, f32x4* cHi, f32x4* nLo, f32x4* nHi, int i){
      if (i + 1 < 8){
        const float* np = rowp + (size_t)(i+1)*128;
        #pragma unroll
        for (int kt=0; kt<4; ++kt){
          nLo[kt] = *(const f32x4*)(np + kt*32);
          nHi[kt] = *(const f32x4*)(np + kt*32 + 4);
        }
      }
      bf16x8 xa[4];
      #pragma unroll
      for (int kt=0; kt<4; ++kt){
        BF8 u;
        #pragma unroll
        for (int j=0;j<4;++j){ u.s[j]=f2bf(cLo[kt][j]); u.s[4+j]=f2bf(cHi[kt][j]); }
        xa[kt] = u.v;
      }
      f32x4 acc[16];
      #pragma unroll
      for (int g=0; g<16; ++g) acc[g] = (f32x4){bias[g],bias[g],bias[g],bias[g]};
      #pragma unroll
      for (int kt=0; kt<4; ++kt){
        #pragma unroll
        for (int g=0; g<16; ++g){
          int row = g*16 + col4;
          const bf16x8 b = *(const bf16x8*)(Wlds + row*128 + (((kt*4+grp) ^ (row&7))<<3));
          acc[g] = __builtin_amdgcn_mfma_f32_16x16x32_bf16(xa[kt], b, acc[g], 0,0,0);
        }
      }
      // 64 bf16/lane, [j][lane] interleave, 8KB contiguous per (tile,t)
      const int t = th*8 + i;
      bf16x8* dstp = (bf16x8*)girz + ((size_t)(tile*16 + t)*8)*64;
      #pragma unroll
      for (int j=0; j<8; ++j){
        BF8 u;
        #pragma unroll
        for (int e=0; e<8; ++e){
          int idx = j*8+e;
          u.s[e] = f2bf(acc[idx>>2][idx&3]);
        }
        dstp[j*64 + lane] = u.v;
      }
    };

    for (int i = 0; i < 8; i += 2){
      body(Alo, Ahi, Blo, Bhi, i);
      body(Blo, Bhi, Alo, Ahi, i+1);
    }
  }
}

// ---------------- phase B2: fused sequential GRU (h-gates + x-n-gate) ----------------
__global__ __launch_bounds__(384) void k_phB2(
    const unsigned short* __restrict__ Whh_sw, const unsigned short* __restrict__ Wihn,
    const float* __restrict__ bih, const float* __restrict__ bhh,
    const float* __restrict__ seq, const unsigned short* __restrict__ girz,
    float* __restrict__ hout, int nT, int N)
{
  __shared__ unsigned short Whlds[49152];   // 96KB: Whh 384x128
  __shared__ unsigned short Wnlds[16384];   // 32KB: Wih_n 128x128
  __shared__ unsigned short hbuf[6][2048];  // 24KB: per-wave h transpose
  const int tid = threadIdx.x;
  for (int i = tid; i < 6144; i += 384) ((uint4*)Whlds)[i] = ((const uint4*)Whh_sw)[i];
  for (int i = tid; i < 2048; i += 384) ((uint4*)Wnlds)[i] = ((const uint4*)Wihn)[i];
  __syncthreads();
  const int lane = tid & 63, wloc = tid >> 6;
  const int col4 = lane & 15, grp = lane >> 4;
  const int tile = wloc*gridDim.x + blockIdx.x;
  if (tile >= nT) return;
  unsigned short* myh = hbuf[wloc];

  float bin8[8], bhn8[8];
  #pragma unroll
  for (int ct=0; ct<8; ++ct){
    int c = 256 + ct*16 + col4;
    bin8[ct] = bih[c]; bhn8[ct] = bhh[c];
  }

  int nrow = tile*16 + col4; if (nrow >= N) nrow = N-1;
  const float* rowp = seq + (size_t)nrow*16*128 + grp*8;

  float h[8][4];
  #pragma unroll
  for (int ct=0;ct<8;++ct)
    #pragma unroll
    for (int q=0;q<4;++q) h[ct][q] = 0.0f;

  f32x4 xlo[4], xhi[4];
  #pragma unroll
  for (int kt=0; kt<4; ++kt){
    xlo[kt] = *(const f32x4*)(rowp + kt*32);
    xhi[kt] = *(const f32x4*)(rowp + kt*32 + 4);
  }

  for (int t=0; t<16; ++t){
    bf16x8 xa[4];
    #pragma unroll
    for (int kt=0; kt<4; ++kt){
      BF8 u;
      #pragma unroll
      for (int j=0;j<4;++j){ u.s[j]=f2bf(xlo[kt][j]); u.s[4+j]=f2bf(xhi[kt][j]); }
      xa[kt] = u.v;
    }
    if (t < 15){
      const float* np = rowp + (size_t)(t+1)*128;
      #pragma unroll
      for (int kt=0; kt<4; ++kt){
        xlo[kt] = *(const f32x4*)(np + kt*32);
        xhi[kt] = *(const f32x4*)(np + kt*32 + 4);
      }
    }
    // issue gi_rz loads early; first use is after the MFMA block
    const bf16x8* gp = (const bf16x8*)girz + ((size_t)(tile*16 + t)*8)*64;
    BF8 g8[8];
    #pragma unroll
    for (int j=0;j<8;++j) g8[j].v = gp[j*64 + lane];

    bf16x8 ha[4];
    if (t == 0){
      BF8 uz;
      #pragma unroll
      for (int j=0;j<8;++j) uz.s[j]=0;
      #pragma unroll
      for (int kt=0;kt<4;++kt) ha[kt]=uz.v;
    } else {
      #pragma unroll
      for (int kt=0;kt<4;++kt){
        int ck = (kt*4+grp) ^ (col4&7);
        ha[kt] = *(const bf16x8*)(myh + col4*128 + ck*8);
      }
    }

    #pragma unroll
    for (int hf=0; hf<2; ++hf){
      f32x4 a_r[4], a_z[4], a_hn[4], a_xn[4];
      #pragma unroll
      for (int j=0;j<4;++j){
        a_r[j] = (f32x4)0.0f; a_z[j] = (f32x4)0.0f;
        float b1 = bhn8[hf*4+j], b2 = bin8[hf*4+j];
        a_hn[j] = (f32x4){b1,b1,b1,b1};
        a_xn[j] = (f32x4){b2,b2,b2,b2};
      }
      #pragma unroll
      for (int kt=0;kt<4;++kt){
        #pragma unroll
        for (int j=0;j<4;++j){
          int ct = hf*4+j;
          int rr = ct*16 + col4;                       // row within each gate block
          int sw = (((kt*4+grp) ^ (rr&7))<<3);
          const bf16x8 br = *(const bf16x8*)(Whlds + (      rr)*128 + sw);
          const bf16x8 bz = *(const bf16x8*)(Whlds + (128 + rr)*128 + sw);
          const bf16x8 bh = *(const bf16x8*)(Whlds + (256 + rr)*128 + sw);
          const bf16x8 bx = *(const bf16x8*)(Wnlds + (      rr)*128 + sw);
          a_r [j] = __builtin_amdgcn_mfma_f32_16x16x32_bf16(ha[kt], br, a_r [j], 0,0,0);
          a_z [j] = __builtin_amdgcn_mfma_f32_16x16x32_bf16(ha[kt], bz, a_z [j], 0,0,0);
          a_hn[j] = __builtin_amdgcn_mfma_f32_16x16x32_bf16(ha[kt], bh, a_hn[j], 0,0,0);
          a_xn[j] = __builtin_amdgcn_mfma_f32_16x16x32_bf16(xa[kt], bx, a_xn[j], 0,0,0);
        }
      }
      #pragma unroll
      for (int j=0;j<4;++j){
        int ct = hf*4+j;
        #pragma unroll
        for (int q=0;q<4;++q){
          int idr = ct*4+q, idz = 32+ct*4+q;
          float gr = a_r[j][q] + bf2f(g8[idr>>3].s[idr&7]);
          float gz = a_z[j][q] + bf2f(g8[idz>>3].s[idz&7]);
          float r = sigm(gr), z = sigm(gz);
          float nn = tanh_fast(a_xn[j][q] + r * a_hn[j][q]);
          float hv = h[ct][q];
          hv = nn + z*(hv - nn);
          h[ct][q] = hv;
          int m = grp*4 + q, c = ct*16 + col4;
          int c2 = (c>>3) ^ (m&7);
          myh[m*128 + c2*8 + (c&7)] = f2bf(hv);
        }
      }
    }
  }
  #pragma unroll
  for (int ct=0;ct<8;++ct)
    #pragma unroll
    for (int q=0;q<4;++q){
      int n = tile*16 + grp*4 + q;
      if (n < N) hout[(size_t)n*128 + ct*16 + col4] = h[ct][q];
    }
}

// ---------------- GAT linear (MFMA) + fused attention scalars; x stored bf16 ----------------
__global__ __launch_bounds__(256) void k_gat1(
    const float* __restrict__ hsrc, const unsigned short* __restrict__ lin_sw,
    const float* __restrict__ att_s, const float* __restrict__ att_d,
    unsigned short* __restrict__ xbf, float* __restrict__ a_s, float* __restrict__ a_d,
    int N, int nT)
{
  __shared__ unsigned short Llds[16384];
  const int tid = threadIdx.x;
  for (int i = tid; i < 2048; i += 256)
    ((uint4*)Llds)[i] = ((const uint4*)lin_sw)[i];
  __syncthreads();
  const int lane = tid & 63, wloc = tid >> 6;
  const int col4 = lane & 15, grp = lane >> 4;
  const int tile = blockIdx.x*4 + wloc;
  if (tile >= nT) return;
  float ats[8], atd[8];
  #pragma unroll
  for (int ct=0;ct<8;++ct){ ats[ct] = att_s[ct*16+col4]; atd[ct] = att_d[ct*16+col4]; }
  int nrow = tile*16 + col4; if (nrow >= N) nrow = N-1;
  const float* xr = hsrc + (size_t)nrow*128 + grp*8;
  bf16x8 xa[4];
  #pragma unroll
  for (int kt=0;kt<4;++kt){
    f32x4 lo = *(const f32x4*)(xr + kt*32);
    f32x4 hi = *(const f32x4*)(xr + kt*32 + 4);
    BF8 u;
    #pragma unroll
    for (int j=0;j<4;++j){ u.s[j]=f2bf(lo[j]); u.s[4+j]=f2bf(hi[j]); }
    xa[kt] = u.v;
  }
  f32x4 acc[8];
  #pragma unroll
  for (int ct=0;ct<8;++ct) acc[ct] = (f32x4)0.0f;
  #pragma unroll
  for (int kt=0;kt<4;++kt){
    #pragma unroll
    for (int ct=0;ct<8;++ct){
      int row = ct*16+col4;
      const bf16x8 b = *(const bf16x8*)(Llds + row*128 + (((kt*4+grp)^(row&7))<<3));
      acc[ct] = __builtin_amdgcn_mfma_f32_16x16x32_bf16(xa[kt], b, acc[ct], 0,0,0);
    }
  }
  float ss[4] = {0,0,0,0}, dd[4] = {0,0,0,0};
  #pragma unroll
  for (int ct=0;ct<8;++ct)
    #pragma unroll
    for (int q=0;q<4;++q){
      float xv = acc[ct][q];
      int n = tile*16 + grp*4 + q;
      if (n < N) xbf[(size_t)n*128 + ct*16 + col4] = f2bf(xv);
      ss[q] += xv * ats[ct];
      dd[q] += xv * atd[ct];
    }
  #pragma unroll
  for (int m=1; m<16; m<<=1){
    #pragma unroll
    for (int q=0;q<4;++q){
      ss[q] += __shfl_xor(ss[q], m);
      dd[q] += __shfl_xor(dd[q], m);
    }
  }
  if (col4 == 0){
    #pragma unroll
    for (int q=0;q<4;++q){
      int n = tile*16 + grp*4 + q;
      if (n < N){ a_s[n] = ss[q]; a_d[n] = dd[q]; }
    }
  }
}

// ---------------- CSR aggregation: one wave per destination node, no atomics ----------------
__global__ __launch_bounds__(256) void k_agg2(
    const int* __restrict__ off, const int* __restrict__ eid,
    const float* __restrict__ a_s, const float* __restrict__ a_d,
    const unsigned short* __restrict__ xbf, const float* __restrict__ bias,
    float* __restrict__ out2, int N)
{
  int d = blockIdx.x*4 + (threadIdx.x >> 6);
  if (d >= N) return;
  const int lane = threadIdx.x & 63;
  const unsigned* xw = (const unsigned*)xbf;   // 2 bf16 channels per uint
  const float ad_d = a_d[d];
  float a0 = a_s[d] + ad_d; a0 = a0 > 0.f ? a0 : 0.2f*a0;
  float w = __expf(a0);
  unsigned pv = xw[(size_t)d*64 + lane];
  float den  = w;
  float acc0 = w * bf2f((unsigned short)(pv & 0xffffu));
  float acc1 = w * bf2f((unsigned short)(pv >> 16));
  const int i1 = off[d+1];
  for (int i = off[d]; i < i1; ++i){
    int s = eid[i];
    float a = a_s[s] + ad_d; a = a > 0.f ? a : 0.2f*a;
    float ww = __expf(a);
    unsigned pp = xw[(size_t)s*64 + lane];
    den  += ww;
    acc0 += ww * bf2f((unsigned short)(pp & 0xffffu));
    acc1 += ww * bf2f((unsigned short)(pp >> 16));
  }
  float inv = 1.0f/den;
  float2 o;
  o.x = acc0*inv + bias[2*lane];
  o.y = acc1*inv + bias[2*lane+1];
  *(float2*)(out2 + (size_t)d*128 + 2*lane) = o;
}

extern "C" void kernel_launch(void* const* d_in, const int* in_sizes, int n_in,
                              void* d_out, int out_size, void* d_ws, size_t ws_size,
                              hipStream_t stream)
{
  const float* seq  = (const float*)d_in[0];
  const void*  ei   = d_in[1];
  const float* Wihf = (const float*)d_in[2];
  const float* Whhf = (const float*)d_in[3];
  const float* bih  = (const float*)d_in[4];
  const float* bhh  = (const float*)d_in[5];
  const float* linw = (const float*)d_in[6];
  const float* atts = (const float*)d_in[7];
  const float* attd = (const float*)d_in[8];
  const float* gbias= (const float*)d_in[9];

  const int N  = in_sizes[0] / (16*128);
  const int E  = in_sizes[1] / 2;
  const int nT = (N + 15) / 16;

  char* ws = (char*)d_ws;
  size_t off_b = 0;
  auto alloc = [&](size_t bytes) -> char* {
    char* p = ws + off_b;
    off_b = (off_b + bytes + 255) & ~(size_t)255;
    return p;
  };
  unsigned short* Wihrz  = (unsigned short*)alloc(65536);
  unsigned short* Wihn   = (unsigned short*)alloc(32768);
  unsigned short* Whh_sw = (unsigned short*)alloc(98304);
  unsigned short* lin_sw = (unsigned short*)alloc(32768);
  unsigned short* xbf    = (unsigned short*)alloc((size_t)N*128*2);
  float*    a_s    = (float*)   alloc((size_t)N*4);
  float*    a_d    = (float*)   alloc((size_t)N*4);
  unsigned* flag   = (unsigned*)alloc(64);
  int*      srcA   = (int*)     alloc((size_t)E*4);
  int*      dstA   = (int*)     alloc((size_t)E*4);
  int*      deg    = (int*)     alloc((size_t)N*4);
  int*      offs   = (int*)     alloc((size_t)(N+1)*4);
  int*      cur    = (int*)     alloc((size_t)N*4);
  int*      eid    = (int*)     alloc((size_t)E*4);
  unsigned short* girz = (unsigned short*)alloc((size_t)nT*16*8192);  // 164MB @ N=20000

  float* hout = (float*)d_out;
  float* out2 = hout + (size_t)N*128;

  k_prep   <<<448, 256, 0, stream>>>(Wihf, Whhf, linw, Wihrz, Wihn, Whh_sw, lin_sw);
  k_detect <<<1, 64, 0, stream>>>((const int*)ei, flag);
  k_zero   <<<(N + 255)/256, 256, 0, stream>>>(deg, N);
  k_norm   <<<(E + 255)/256, 256, 0, stream>>>(ei, flag, srcA, dstA, deg, E);
  k_scan   <<<1, 64, 0, stream>>>(deg, offs, cur, N);
  k_scatter<<<(E + 255)/256, 256, 0, stream>>>(srcA, dstA, offs, cur, eid, E);

  k_phA2<<<512, 512, 0, stream>>>(seq, Wihrz, bih, bhh, girz, nT, N);
  int gB = (nT + 5)/6; if (gB < 256) gB = 256;
  k_phB2<<<gB, 384, 0, stream>>>(Whh_sw, Wihn, bih, bhh, seq, girz, hout, nT, N);

  k_gat1<<<(nT + 3)/4, 256, 0, stream>>>(hout, lin_sw, atts, attd, xbf, a_s, a_d, N, nT);
  k_agg2<<<(N + 3)/4, 256, 0, stream>>>(offs, eid, a_s, a_d, xbf, gbias, out2, N);
}

// Round 6
// 426.099 us; speedup vs baseline: 2.8619x; 2.7055x over previous
//
#include <hip/hip_runtime.h>

typedef __bf16 bf16x8 __attribute__((ext_vector_type(8)));
typedef float  f32x4  __attribute__((ext_vector_type(4)));
union BF8 { unsigned short s[8]; bf16x8 v; };

__device__ __forceinline__ unsigned short f2bf(float x){
  unsigned u = __float_as_uint(x);
  u += 0x7fffu + ((u >> 16) & 1u);      // round-to-nearest-even
  return (unsigned short)(u >> 16);
}
__device__ __forceinline__ float bf2f(unsigned short s){ return __uint_as_float(((unsigned)s) << 16); }
__device__ __forceinline__ float sigm(float x){ return 1.0f/(1.0f + __expf(-x)); }
__device__ __forceinline__ float tanh_fast(float x){ return 1.0f - 2.0f/(__expf(2.0f*x)+1.0f); }

// ---------------- prep: W -> bf16 pre-swizzled (chunk-of-8 ^ (row&7)) ----------------
__global__ void k_prep(const float* __restrict__ Wihf, const float* __restrict__ Whhf,
                       const float* __restrict__ linw,
                       unsigned short* __restrict__ Wih_sw, unsigned short* __restrict__ Whh_sw,
                       unsigned short* __restrict__ lin_sw)
{
  int tid = blockIdx.x*256 + threadIdx.x;
  if (tid < 49152){
    int row = tid >> 7, col = tid & 127;
    Wih_sw[row*128 + (((col>>3) ^ (row&7))<<3) + (col&7)] = f2bf(Wihf[tid]);
  } else if (tid < 98304){
    int i = tid - 49152; int row = i >> 7, col = i & 127;
    Whh_sw[row*128 + (((col>>3) ^ (row&7))<<3) + (col&7)] = f2bf(Whhf[i]);
  } else if (tid < 114688){
    int i = tid - 98304; int row = i >> 7, col = i & 127;
    lin_sw[row*128 + (((col>>3) ^ (row&7))<<3) + (col&7)] = f2bf(linw[i]);
  }
}

// ---------------- edge index dtype sniff ----------------
__global__ void k_detect(const int* __restrict__ ei, unsigned* __restrict__ flag){
  int v = ei[2*threadIdx.x + 1];
  unsigned long long b = __ballot(v == 0);
  if (threadIdx.x == 0) flag[0] = (b == ~0ULL) ? 1u : 0u;
}

__global__ void k_zero(int* __restrict__ deg, int N){
  int tid = blockIdx.x*256 + threadIdx.x;
  if (tid < N) deg[tid] = 0;
}

__global__ void k_norm(const void* __restrict__ ei, const unsigned* __restrict__ flag,
                       int* __restrict__ src, int* __restrict__ dst, int* __restrict__ deg, int E){
  int e = blockIdx.x*256 + threadIdx.x;
  if (e >= E) return;
  int s, d;
  if (flag[0]){
    const long long* p = (const long long*)ei;
    s = (int)p[e]; d = (int)p[(size_t)E + e];
  } else {
    const int* p = (const int*)ei;
    s = p[e]; d = p[E + e];
  }
  src[e] = s; dst[e] = d;
  atomicAdd(&deg[d], 1);
}

__global__ void k_scan(const int* __restrict__ deg, int* __restrict__ off,
                       int* __restrict__ cur, int N){
  int lane = threadIdx.x;
  int carry = 0;
  for (int base = 0; base < N; base += 64){
    int i = base + lane;
    int v = (i < N) ? deg[i] : 0;
    int inc = v;
    #pragma unroll
    for (int d2 = 1; d2 < 64; d2 <<= 1){
      int u = __shfl_up(inc, d2);
      if (lane >= d2) inc += u;
    }
    if (i < N){ off[i] = carry + inc - v; cur[i] = 0; }
    carry += __shfl(inc, 63);
  }
  if (lane == 0) off[N] = carry;
}

__global__ void k_scatter(const int* __restrict__ src, const int* __restrict__ dst,
                          const int* __restrict__ off, int* __restrict__ cur,
                          int* __restrict__ eid, int E){
  int e = blockIdx.x*256 + threadIdx.x;
  if (e >= E) return;
  int d = dst[e];
  int p = off[d] + atomicAdd(&cur[d], 1);
  eid[p] = src[e];
}

// ---------------- fused GRU: weights in registers, channel-split across 8 waves ---------
// Block = 8 waves = one 16-node tile, all 16 timesteps. Wave w owns channels [16w,16w+16)
// of each gate. D[row=node(grp*4+q)][col=ch(col4)]; A = x/h node-frags; B = weight frags.
__global__ __launch_bounds__(512, 2) void k_gru_fused(
    const unsigned short* __restrict__ Wih_sw, const unsigned short* __restrict__ Whh_sw,
    const float* __restrict__ bih, const float* __restrict__ bhh,
    const float* __restrict__ seq, float* __restrict__ hout, int nT, int N)
{
  __shared__ unsigned short xbuf[2][16*256];   // [buf][node][s(2 steps)][ch swz]  8KB each
  __shared__ unsigned short hbuf[2][16*128];   // [buf][node][ch swz]              4KB each
  const int tid  = threadIdx.x;
  const int lane = tid & 63, w = tid >> 6;     // w = channel chunk 0..7
  const int col4 = lane & 15, grp = lane >> 4;
  const int tile = blockIdx.x;
  const int ch   = 16*w + col4;                // this lane's output channel

  // ---- weight B-fragments into registers (once per block) ----
  // slab: 0=ih_r 1=ih_z 2=ih_n 3=hh_r 4=hh_z 5=hh_n
  bf16x8 Wf[6][4];
  #pragma unroll
  for (int s6=0; s6<6; ++s6){
    const unsigned short* Wp = (s6 < 3) ? Wih_sw : Whh_sw;
    int row = (s6 % 3)*128 + ch;
    #pragma unroll
    for (int kt=0; kt<4; ++kt)
      Wf[s6][kt] = *(const bf16x8*)(Wp + row*128 + (((kt*4+grp) ^ (row&7))<<3));
  }
  const float brz_r = bih[ch]       + bhh[ch];
  const float brz_z = bih[128 + ch] + bhh[128 + ch];
  const float b_xn  = bih[256 + ch];
  const float b_hn  = bhh[256 + ch];

  float hreg[4] = {0.f, 0.f, 0.f, 0.f};

  // ---- staging helpers: wave w stages node rows 2w, 2w+1; 1KB contiguous per row ----
  f32x4 sv[2];
  auto stageIssue = [&](int tp){
    #pragma unroll
    for (int rr=0; rr<2; ++rr){
      int nrow = tile*16 + 2*w + rr; if (nrow >= N) nrow = N-1;
      sv[rr] = *(const f32x4*)(seq + ((size_t)nrow*16 + tp)*128 + lane*4);
    }
  };
  auto stageWrite = [&](int buf){
    const int s  = lane >> 5;
    const int c0 = (lane & 31) * 4;
    #pragma unroll
    for (int rr=0; rr<2; ++rr){
      int node = 2*w + rr;
      int chunk = (c0 >> 3) ^ node;
      unsigned pk0 = (unsigned)f2bf(sv[rr][0]) | ((unsigned)f2bf(sv[rr][1]) << 16);
      unsigned pk1 = (unsigned)f2bf(sv[rr][2]) | ((unsigned)f2bf(sv[rr][3]) << 16);
      uint2 pk = {pk0, pk1};
      *(uint2*)(&xbuf[buf][node*256 + s*128 + chunk*8 + (c0 & 7)]) = pk;
    }
  };

  // prologue: pairs 0 and 1
  stageIssue(0); stageWrite(0);
  stageIssue(2);
  __syncthreads();

  for (int t=0; t<16; ++t){
    // A-fragments
    bf16x8 xa[4], ha[4];
    {
      const unsigned short* xb = xbuf[(t>>1)&1] + col4*256 + (t&1)*128;
      #pragma unroll
      for (int kt=0;kt<4;++kt){
        int chunk = (kt*4+grp) ^ col4;
        xa[kt] = *(const bf16x8*)(xb + chunk*8);
      }
    }
    if (t == 0){
      BF8 uz;
      #pragma unroll
      for (int j=0;j<8;++j) uz.s[j]=0;
      #pragma unroll
      for (int kt=0;kt<4;++kt) ha[kt]=uz.v;
    } else {
      const unsigned short* hb = hbuf[t&1];
      #pragma unroll
      for (int kt=0;kt<4;++kt){
        int chunk = (kt*4+grp) ^ col4;
        ha[kt] = *(const bf16x8*)(hb + col4*128 + chunk*8);
      }
    }
    // staging: at even t, write pair t/2+1 (issued 2 steps ago), issue pair t/2+2
    if ((t & 1) == 0){
      int pw = t/2 + 1;
      if (pw <= 7) stageWrite(pw & 1);
      int pi = t/2 + 2;
      if (pi <= 7) stageIssue(pi*2);
    }
    // MFMAs
    f32x4 acc_r  = (f32x4){brz_r, brz_r, brz_r, brz_r};
    f32x4 acc_z  = (f32x4){brz_z, brz_z, brz_z, brz_z};
    f32x4 acc_xn = (f32x4){b_xn,  b_xn,  b_xn,  b_xn };
    f32x4 acc_hn = (f32x4){b_hn,  b_hn,  b_hn,  b_hn };
    #pragma unroll
    for (int kt=0; kt<4; ++kt){
      acc_r  = __builtin_amdgcn_mfma_f32_16x16x32_bf16(xa[kt], Wf[0][kt], acc_r , 0,0,0);
      acc_z  = __builtin_amdgcn_mfma_f32_16x16x32_bf16(xa[kt], Wf[1][kt], acc_z , 0,0,0);
      acc_xn = __builtin_amdgcn_mfma_f32_16x16x32_bf16(xa[kt], Wf[2][kt], acc_xn, 0,0,0);
      acc_r  = __builtin_amdgcn_mfma_f32_16x16x32_bf16(ha[kt], Wf[3][kt], acc_r , 0,0,0);
      acc_z  = __builtin_amdgcn_mfma_f32_16x16x32_bf16(ha[kt], Wf[4][kt], acc_z , 0,0,0);
      acc_hn = __builtin_amdgcn_mfma_f32_16x16x32_bf16(ha[kt], Wf[5][kt], acc_hn, 0,0,0);
    }
    // gates + h update (all lane-local)
    unsigned short* hbw = hbuf[(t+1)&1];
    #pragma unroll
    for (int q=0; q<4; ++q){
      float r  = sigm(acc_r[q]);
      float z  = sigm(acc_z[q]);
      float nn = tanh_fast(acc_xn[q] + r*acc_hn[q]);
      float hv = nn + z*(hreg[q] - nn);
      hreg[q] = hv;
      if (t < 15){
        int node  = grp*4 + q;
        int chunk = (ch >> 3) ^ node;
        hbw[node*128 + chunk*8 + (ch & 7)] = f2bf(hv);
      }
    }
    __syncthreads();
  }

  // write final hidden state: lane (ch, nodes grp*4+q)
  #pragma unroll
  for (int q=0; q<4; ++q){
    int n = tile*16 + grp*4 + q;
    if (n < N) hout[(size_t)n*128 + ch] = hreg[q];
  }
}

// ---------------- GAT linear (MFMA) + fused attention scalars; x stored bf16 ----------------
__global__ __launch_bounds__(256) void k_gat1(
    const float* __restrict__ hsrc, const unsigned short* __restrict__ lin_sw,
    const float* __restrict__ att_s, const float* __restrict__ att_d,
    unsigned short* __restrict__ xbf, float* __restrict__ a_s, float* __restrict__ a_d,
    int N, int nT)
{
  __shared__ unsigned short Llds[16384];
  const int tid = threadIdx.x;
  for (int i = tid; i < 2048; i += 256)
    ((uint4*)Llds)[i] = ((const uint4*)lin_sw)[i];
  __syncthreads();
  const int lane = tid & 63, wloc = tid >> 6;
  const int col4 = lane & 15, grp = lane >> 4;
  const int tile = blockIdx.x*4 + wloc;
  if (tile >= nT) return;
  float ats[8], atd[8];
  #pragma unroll
  for (int ct=0;ct<8;++ct){ ats[ct] = att_s[ct*16+col4]; atd[ct] = att_d[ct*16+col4]; }
  int nrow = tile*16 + col4; if (nrow >= N) nrow = N-1;
  const float* xr = hsrc + (size_t)nrow*128 + grp*8;
  bf16x8 xa[4];
  #pragma unroll
  for (int kt=0;kt<4;++kt){
    f32x4 lo = *(const f32x4*)(xr + kt*32);
    f32x4 hi = *(const f32x4*)(xr + kt*32 + 4);
    BF8 u;
    #pragma unroll
    for (int j=0;j<4;++j){ u.s[j]=f2bf(lo[j]); u.s[4+j]=f2bf(hi[j]); }
    xa[kt] = u.v;
  }
  f32x4 acc[8];
  #pragma unroll
  for (int ct=0;ct<8;++ct) acc[ct] = (f32x4)0.0f;
  #pragma unroll
  for (int kt=0;kt<4;++kt){
    #pragma unroll
    for (int ct=0;ct<8;++ct){
      int row = ct*16+col4;
      const bf16x8 b = *(const bf16x8*)(Llds + row*128 + (((kt*4+grp)^(row&7))<<3));
      acc[ct] = __builtin_amdgcn_mfma_f32_16x16x32_bf16(xa[kt], b, acc[ct], 0,0,0);
    }
  }
  float ss[4] = {0,0,0,0}, dd[4] = {0,0,0,0};
  #pragma unroll
  for (int ct=0;ct<8;++ct)
    #pragma unroll
    for (int q=0;q<4;++q){
      float xv = acc[ct][q];
      int n = tile*16 + grp*4 + q;
      if (n < N) xbf[(size_t)n*128 + ct*16 + col4] = f2bf(xv);
      ss[q] += xv * ats[ct];
      dd[q] += xv * atd[ct];
    }
  #pragma unroll
  for (int m=1; m<16; m<<=1){
    #pragma unroll
    for (int q=0;q<4;++q){
      ss[q] += __shfl_xor(ss[q], m);
      dd[q] += __shfl_xor(dd[q], m);
    }
  }
  if (col4 == 0){
    #pragma unroll
    for (int q=0;q<4;++q){
      int n = tile*16 + grp*4 + q;
      if (n < N){ a_s[n] = ss[q]; a_d[n] = dd[q]; }
    }
  }
}

// ---------------- CSR aggregation: one wave per destination node, no atomics ----------------
__global__ __launch_bounds__(256) void k_agg2(
    const int* __restrict__ off, const int* __restrict__ eid,
    const float* __restrict__ a_s, const float* __restrict__ a_d,
    const unsigned short* __restrict__ xbf, const float* __restrict__ bias,
    float* __restrict__ out2, int N)
{
  int d = blockIdx.x*4 + (threadIdx.x >> 6);
  if (d >= N) return;
  const int lane = threadIdx.x & 63;
  const unsigned* xw = (const unsigned*)xbf;   // 2 bf16 channels per uint
  const float ad_d = a_d[d];
  float a0 = a_s[d] + ad_d; a0 = a0 > 0.f ? a0 : 0.2f*a0;
  float w = __expf(a0);
  unsigned pv = xw[(size_t)d*64 + lane];
  float den  = w;
  float acc0 = w * bf2f((unsigned short)(pv & 0xffffu));
  float acc1 = w * bf2f((unsigned short)(pv >> 16));
  const int i1 = off[d+1];
  for (int i = off[d]; i < i1; ++i){
    int s = eid[i];
    float a = a_s[s] + ad_d; a = a > 0.f ? a : 0.2f*a;
    float ww = __expf(a);
    unsigned pp = xw[(size_t)s*64 + lane];
    den  += ww;
    acc0 += ww * bf2f((unsigned short)(pp & 0xffffu));
    acc1 += ww * bf2f((unsigned short)(pp >> 16));
  }
  float inv = 1.0f/den;
  float2 o;
  o.x = acc0*inv + bias[2*lane];
  o.y = acc1*inv + bias[2*lane+1];
  *(float2*)(out2 + (size_t)d*128 + 2*lane) = o;
}

extern "C" void kernel_launch(void* const* d_in, const int* in_sizes, int n_in,
                              void* d_out, int out_size, void* d_ws, size_t ws_size,
                              hipStream_t stream)
{
  const float* seq  = (const float*)d_in[0];
  const void*  ei   = d_in[1];
  const float* Wihf = (const float*)d_in[2];
  const float* Whhf = (const float*)d_in[3];
  const float* bih  = (const float*)d_in[4];
  const float* bhh  = (const float*)d_in[5];
  const float* linw = (const float*)d_in[6];
  const float* atts = (const float*)d_in[7];
  const float* attd = (const float*)d_in[8];
  const float* gbias= (const float*)d_in[9];

  const int N  = in_sizes[0] / (16*128);
  const int E  = in_sizes[1] / 2;
  const int nT = (N + 15) / 16;

  char* ws = (char*)d_ws;
  size_t off_b = 0;
  auto alloc = [&](size_t bytes) -> char* {
    char* p = ws + off_b;
    off_b = (off_b + bytes + 255) & ~(size_t)255;
    return p;
  };
  unsigned short* Wih_sw = (unsigned short*)alloc(98304);
  unsigned short* Whh_sw = (unsigned short*)alloc(98304);
  unsigned short* lin_sw = (unsigned short*)alloc(32768);
  unsigned short* xbf    = (unsigned short*)alloc((size_t)N*128*2);
  float*    a_s    = (float*)   alloc((size_t)N*4);
  float*    a_d    = (float*)   alloc((size_t)N*4);
  unsigned* flag   = (unsigned*)alloc(64);
  int*      srcA   = (int*)     alloc((size_t)E*4);
  int*      dstA   = (int*)     alloc((size_t)E*4);
  int*      deg    = (int*)     alloc((size_t)N*4);
  int*      offs   = (int*)     alloc((size_t)(N+1)*4);
  int*      cur    = (int*)     alloc((size_t)N*4);
  int*      eid    = (int*)     alloc((size_t)E*4);

  float* hout = (float*)d_out;
  float* out2 = hout + (size_t)N*128;

  k_prep   <<<448, 256, 0, stream>>>(Wihf, Whhf, linw, Wih_sw, Whh_sw, lin_sw);
  k_detect <<<1, 64, 0, stream>>>((const int*)ei, flag);
  k_zero   <<<(N + 255)/256, 256, 0, stream>>>(deg, N);
  k_norm   <<<(E + 255)/256, 256, 0, stream>>>(ei, flag, srcA, dstA, deg, E);
  k_scan   <<<1, 64, 0, stream>>>(deg, offs, cur, N);
  k_scatter<<<(E + 255)/256, 256, 0, stream>>>(srcA, dstA, offs, cur, eid, E);

  k_gru_fused<<<nT, 512, 0, stream>>>(Wih_sw, Whh_sw, bih, bhh, seq, hout, nT, N);

  k_gat1<<<(nT + 3)/4, 256, 0, stream>>>(hout, lin_sw, atts, attd, xbf, a_s, a_d, N, nT);
  k_agg2<<<(N + 3)/4, 256, 0, stream>>>(offs, eid, a_s, a_d, xbf, gbias, out2, N);
}

// Round 7
// 279.281 us; speedup vs baseline: 4.3664x; 1.5257x over previous
//
#include <hip/hip_runtime.h>

typedef __bf16 bf16x8 __attribute__((ext_vector_type(8)));
typedef float  f32x4  __attribute__((ext_vector_type(4)));
union BF8 { unsigned short s[8]; bf16x8 v; };

__device__ __forceinline__ unsigned short f2bf(float x){
  unsigned u = __float_as_uint(x);
  u += 0x7fffu + ((u >> 16) & 1u);      // round-to-nearest-even
  return (unsigned short)(u >> 16);
}
__device__ __forceinline__ float bf2f(unsigned short s){ return __uint_as_float(((unsigned)s) << 16); }
__device__ __forceinline__ float sigm(float x){ return 1.0f/(1.0f + __expf(-x)); }
__device__ __forceinline__ float tanh_fast(float x){ return 1.0f - 2.0f/(__expf(2.0f*x)+1.0f); }

// ---------------- prep: W -> bf16 pre-swizzled (chunk-of-8 ^ (row&7)) ----------------
__global__ void k_prep(const float* __restrict__ Wihf, const float* __restrict__ Whhf,
                       const float* __restrict__ linw,
                       unsigned short* __restrict__ Wih_sw, unsigned short* __restrict__ Whh_sw,
                       unsigned short* __restrict__ lin_sw)
{
  int tid = blockIdx.x*256 + threadIdx.x;
  if (tid < 49152){
    int row = tid >> 7, col = tid & 127;
    Wih_sw[row*128 + (((col>>3) ^ (row&7))<<3) + (col&7)] = f2bf(Wihf[tid]);
  } else if (tid < 98304){
    int i = tid - 49152; int row = i >> 7, col = i & 127;
    Whh_sw[row*128 + (((col>>3) ^ (row&7))<<3) + (col&7)] = f2bf(Whhf[i]);
  } else if (tid < 114688){
    int i = tid - 98304; int row = i >> 7, col = i & 127;
    lin_sw[row*128 + (((col>>3) ^ (row&7))<<3) + (col&7)] = f2bf(linw[i]);
  }
}

// ---------------- edge index dtype sniff ----------------
__global__ void k_detect(const int* __restrict__ ei, unsigned* __restrict__ flag){
  int v = ei[2*threadIdx.x + 1];
  unsigned long long b = __ballot(v == 0);
  if (threadIdx.x == 0) flag[0] = (b == ~0ULL) ? 1u : 0u;
}

__global__ void k_zero(int* __restrict__ deg, int N){
  int tid = blockIdx.x*256 + threadIdx.x;
  if (tid < N) deg[tid] = 0;
}

__global__ void k_norm(const void* __restrict__ ei, const unsigned* __restrict__ flag,
                       int* __restrict__ src, int* __restrict__ dst, int* __restrict__ deg, int E){
  int e = blockIdx.x*256 + threadIdx.x;
  if (e >= E) return;
  int s, d;
  if (flag[0]){
    const long long* p = (const long long*)ei;
    s = (int)p[e]; d = (int)p[(size_t)E + e];
  } else {
    const int* p = (const int*)ei;
    s = p[e]; d = p[E + e];
  }
  src[e] = s; dst[e] = d;
  atomicAdd(&deg[d], 1);
}

// ---------------- parallel 3-level exclusive scan of deg -> off ----------------
__global__ __launch_bounds__(256) void k_scanA(const int* __restrict__ deg,
    int* __restrict__ off, int* __restrict__ bsum, int N){
  __shared__ int wsum[4];
  const int b = blockIdx.x, t = threadIdx.x;
  const int lane = t & 63, wv = t >> 6;
  const int base = b*1024 + t*4;
  int v[4]; int s = 0;
  #pragma unroll
  for (int j=0;j<4;++j){ v[j] = (base+j < N) ? deg[base+j] : 0; s += v[j]; }
  int inc = s;
  #pragma unroll
  for (int d2=1; d2<64; d2<<=1){ int u = __shfl_up(inc, d2); if (lane >= d2) inc += u; }
  if (lane == 63) wsum[wv] = inc;
  __syncthreads();
  int woff = 0;
  #pragma unroll
  for (int j=0;j<4;++j) if (j < wv) woff += wsum[j];
  int ex = woff + inc - s;
  #pragma unroll
  for (int j=0;j<4;++j){
    if (base+j < N) off[base+j] = ex;
    ex += v[j];
  }
  if (t == 255) bsum[b] = woff + inc;
}

__global__ void k_scanB(int* __restrict__ bsum, int* __restrict__ total, int nB){
  int lane = threadIdx.x;
  int carry = 0;
  for (int base = 0; base < nB; base += 64){
    int i = base + lane;
    int v = (i < nB) ? bsum[i] : 0;
    int inc = v;
    #pragma unroll
    for (int d2=1; d2<64; d2<<=1){ int u = __shfl_up(inc, d2); if (lane >= d2) inc += u; }
    if (i < nB) bsum[i] = carry + inc - v;
    carry += __shfl(inc, 63);
  }
  if (lane == 0) total[0] = carry;
}

__global__ void k_scanC(int* __restrict__ off, const int* __restrict__ bsum,
    const int* __restrict__ total, int* __restrict__ cur, int N){
  int i = blockIdx.x*256 + threadIdx.x;
  if (i < N){ off[i] += bsum[i>>10]; cur[i] = 0; }
  if (i == 0) off[N] = total[0];
}

__global__ void k_scatter(const int* __restrict__ src, const int* __restrict__ dst,
                          const int* __restrict__ off, int* __restrict__ cur,
                          int* __restrict__ eid, int E){
  int e = blockIdx.x*256 + threadIdx.x;
  if (e >= E) return;
  int d = dst[e];
  int p = off[d] + atomicAdd(&cur[d], 1);
  eid[p] = src[e];
}

// ---------------- fused GRU: weights in registers, channel-split across 8 waves ---------
__global__ __launch_bounds__(512, 2) void k_gru_fused(
    const unsigned short* __restrict__ Wih_sw, const unsigned short* __restrict__ Whh_sw,
    const float* __restrict__ bih, const float* __restrict__ bhh,
    const float* __restrict__ seq, float* __restrict__ hout, int nT, int N)
{
  __shared__ unsigned short xbuf[2][16*256];   // [buf][node][s(2 steps)][ch swz]  8KB each
  __shared__ unsigned short hbuf[2][16*128];   // [buf][node][ch swz]              4KB each
  const int tid  = threadIdx.x;
  const int lane = tid & 63, w = tid >> 6;     // w = channel chunk 0..7
  const int col4 = lane & 15, grp = lane >> 4;
  const int tile = blockIdx.x;
  const int ch   = 16*w + col4;                // this lane's output channel

  bf16x8 Wf[6][4];
  #pragma unroll
  for (int s6=0; s6<6; ++s6){
    const unsigned short* Wp = (s6 < 3) ? Wih_sw : Whh_sw;
    int row = (s6 % 3)*128 + ch;
    #pragma unroll
    for (int kt=0; kt<4; ++kt)
      Wf[s6][kt] = *(const bf16x8*)(Wp + row*128 + (((kt*4+grp) ^ (row&7))<<3));
  }
  const float brz_r = bih[ch]       + bhh[ch];
  const float brz_z = bih[128 + ch] + bhh[128 + ch];
  const float b_xn  = bih[256 + ch];
  const float b_hn  = bhh[256 + ch];

  float hreg[4] = {0.f, 0.f, 0.f, 0.f};

  f32x4 sv[2];
  auto stageIssue = [&](int tp){
    #pragma unroll
    for (int rr=0; rr<2; ++rr){
      int nrow = tile*16 + 2*w + rr; if (nrow >= N) nrow = N-1;
      sv[rr] = *(const f32x4*)(seq + ((size_t)nrow*16 + tp)*128 + lane*4);
    }
  };
  auto stageWrite = [&](int buf){
    const int s  = lane >> 5;
    const int c0 = (lane & 31) * 4;
    #pragma unroll
    for (int rr=0; rr<2; ++rr){
      int node = 2*w + rr;
      int chunk = (c0 >> 3) ^ node;
      unsigned pk0 = (unsigned)f2bf(sv[rr][0]) | ((unsigned)f2bf(sv[rr][1]) << 16);
      unsigned pk1 = (unsigned)f2bf(sv[rr][2]) | ((unsigned)f2bf(sv[rr][3]) << 16);
      uint2 pk = {pk0, pk1};
      *(uint2*)(&xbuf[buf][node*256 + s*128 + chunk*8 + (c0 & 7)]) = pk;
    }
  };

  stageIssue(0); stageWrite(0);
  stageIssue(2);
  __syncthreads();

  for (int t=0; t<16; ++t){
    bf16x8 xa[4], ha[4];
    {
      const unsigned short* xb = xbuf[(t>>1)&1] + col4*256 + (t&1)*128;
      #pragma unroll
      for (int kt=0;kt<4;++kt){
        int chunk = (kt*4+grp) ^ col4;
        xa[kt] = *(const bf16x8*)(xb + chunk*8);
      }
    }
    if (t == 0){
      BF8 uz;
      #pragma unroll
      for (int j=0;j<8;++j) uz.s[j]=0;
      #pragma unroll
      for (int kt=0;kt<4;++kt) ha[kt]=uz.v;
    } else {
      const unsigned short* hb = hbuf[t&1];
      #pragma unroll
      for (int kt=0;kt<4;++kt){
        int chunk = (kt*4+grp) ^ col4;
        ha[kt] = *(const bf16x8*)(hb + col4*128 + chunk*8);
      }
    }
    if ((t & 1) == 0){
      int pw = t/2 + 1;
      if (pw <= 7) stageWrite(pw & 1);
      int pi = t/2 + 2;
      if (pi <= 7) stageIssue(pi*2);
    }
    f32x4 acc_r  = (f32x4){brz_r, brz_r, brz_r, brz_r};
    f32x4 acc_z  = (f32x4){brz_z, brz_z, brz_z, brz_z};
    f32x4 acc_xn = (f32x4){b_xn,  b_xn,  b_xn,  b_xn };
    f32x4 acc_hn = (f32x4){b_hn,  b_hn,  b_hn,  b_hn };
    #pragma unroll
    for (int kt=0; kt<4; ++kt){
      acc_r  = __builtin_amdgcn_mfma_f32_16x16x32_bf16(xa[kt], Wf[0][kt], acc_r , 0,0,0);
      acc_z  = __builtin_amdgcn_mfma_f32_16x16x32_bf16(xa[kt], Wf[1][kt], acc_z , 0,0,0);
      acc_xn = __builtin_amdgcn_mfma_f32_16x16x32_bf16(xa[kt], Wf[2][kt], acc_xn, 0,0,0);
      acc_r  = __builtin_amdgcn_mfma_f32_16x16x32_bf16(ha[kt], Wf[3][kt], acc_r , 0,0,0);
      acc_z  = __builtin_amdgcn_mfma_f32_16x16x32_bf16(ha[kt], Wf[4][kt], acc_z , 0,0,0);
      acc_hn = __builtin_amdgcn_mfma_f32_16x16x32_bf16(ha[kt], Wf[5][kt], acc_hn, 0,0,0);
    }
    unsigned short* hbw = hbuf[(t+1)&1];
    #pragma unroll
    for (int q=0; q<4; ++q){
      float r  = sigm(acc_r[q]);
      float z  = sigm(acc_z[q]);
      float nn = tanh_fast(acc_xn[q] + r*acc_hn[q]);
      float hv = nn + z*(hreg[q] - nn);
      hreg[q] = hv;
      if (t < 15){
        int node  = grp*4 + q;
        int chunk = (ch >> 3) ^ node;
        hbw[node*128 + chunk*8 + (ch & 7)] = f2bf(hv);
      }
    }
    __syncthreads();
  }

  #pragma unroll
  for (int q=0; q<4; ++q){
    int n = tile*16 + grp*4 + q;
    if (n < N) hout[(size_t)n*128 + ch] = hreg[q];
  }
}

// ---------------- GAT linear (MFMA) + fused attention scalars; x stored bf16 ----------------
__global__ __launch_bounds__(256) void k_gat1(
    const float* __restrict__ hsrc, const unsigned short* __restrict__ lin_sw,
    const float* __restrict__ att_s, const float* __restrict__ att_d,
    unsigned short* __restrict__ xbf, float* __restrict__ a_s, float* __restrict__ a_d,
    int N, int nT)
{
  __shared__ unsigned short Llds[16384];
  const int tid = threadIdx.x;
  for (int i = tid; i < 2048; i += 256)
    ((uint4*)Llds)[i] = ((const uint4*)lin_sw)[i];
  __syncthreads();
  const int lane = tid & 63, wloc = tid >> 6;
  const int col4 = lane & 15, grp = lane >> 4;
  const int tile = blockIdx.x*4 + wloc;
  if (tile >= nT) return;
  float ats[8], atd[8];
  #pragma unroll
  for (int ct=0;ct<8;++ct){ ats[ct] = att_s[ct*16+col4]; atd[ct] = att_d[ct*16+col4]; }
  int nrow = tile*16 + col4; if (nrow >= N) nrow = N-1;
  const float* xr = hsrc + (size_t)nrow*128 + grp*8;
  bf16x8 xa[4];
  #pragma unroll
  for (int kt=0;kt<4;++kt){
    f32x4 lo = *(const f32x4*)(xr + kt*32);
    f32x4 hi = *(const f32x4*)(xr + kt*32 + 4);
    BF8 u;
    #pragma unroll
    for (int j=0;j<4;++j){ u.s[j]=f2bf(lo[j]); u.s[4+j]=f2bf(hi[j]); }
    xa[kt] = u.v;
  }
  f32x4 acc[8];
  #pragma unroll
  for (int ct=0;ct<8;++ct) acc[ct] = (f32x4)0.0f;
  #pragma unroll
  for (int kt=0;kt<4;++kt){
    #pragma unroll
    for (int ct=0;ct<8;++ct){
      int row = ct*16+col4;
      const bf16x8 b = *(const bf16x8*)(Llds + row*128 + (((kt*4+grp)^(row&7))<<3));
      acc[ct] = __builtin_amdgcn_mfma_f32_16x16x32_bf16(xa[kt], b, acc[ct], 0,0,0);
    }
  }
  float ss[4] = {0,0,0,0}, dd[4] = {0,0,0,0};
  #pragma unroll
  for (int ct=0;ct<8;++ct)
    #pragma unroll
    for (int q=0;q<4;++q){
      float xv = acc[ct][q];
      int n = tile*16 + grp*4 + q;
      if (n < N) xbf[(size_t)n*128 + ct*16 + col4] = f2bf(xv);
      ss[q] += xv * ats[ct];
      dd[q] += xv * atd[ct];
    }
  #pragma unroll
  for (int m=1; m<16; m<<=1){
    #pragma unroll
    for (int q=0;q<4;++q){
      ss[q] += __shfl_xor(ss[q], m);
      dd[q] += __shfl_xor(dd[q], m);
    }
  }
  if (col4 == 0){
    #pragma unroll
    for (int q=0;q<4;++q){
      int n = tile*16 + grp*4 + q;
      if (n < N){ a_s[n] = ss[q]; a_d[n] = dd[q]; }
    }
  }
}

// ---------------- CSR aggregation: one wave per destination node, no atomics ----------------
__global__ __launch_bounds__(256) void k_agg2(
    const int* __restrict__ off, const int* __restrict__ eid,
    const float* __restrict__ a_s, const float* __restrict__ a_d,
    const unsigned short* __restrict__ xbf, const float* __restrict__ bias,
    float* __restrict__ out2, int N)
{
  int d = blockIdx.x*4 + (threadIdx.x >> 6);
  if (d >= N) return;
  const int lane = threadIdx.x & 63;
  const unsigned* xw = (const unsigned*)xbf;   // 2 bf16 channels per uint
  const float ad_d = a_d[d];
  float a0 = a_s[d] + ad_d; a0 = a0 > 0.f ? a0 : 0.2f*a0;
  float w = __expf(a0);
  unsigned pv = xw[(size_t)d*64 + lane];
  float den  = w;
  float acc0 = w * bf2f((unsigned short)(pv & 0xffffu));
  float acc1 = w * bf2f((unsigned short)(pv >> 16));
  const int i1 = off[d+1];
  for (int i = off[d]; i < i1; ++i){
    int s = eid[i];
    float a = a_s[s] + ad_d; a = a > 0.f ? a : 0.2f*a;
    float ww = __expf(a);
    unsigned pp = xw[(size_t)s*64 + lane];
    den  += ww;
    acc0 += ww * bf2f((unsigned short)(pp & 0xffffu));
    acc1 += ww * bf2f((unsigned short)(pp >> 16));
  }
  float inv = 1.0f/den;
  float2 o;
  o.x = acc0*inv + bias[2*lane];
  o.y = acc1*inv + bias[2*lane+1];
  *(float2*)(out2 + (size_t)d*128 + 2*lane) = o;
}

extern "C" void kernel_launch(void* const* d_in, const int* in_sizes, int n_in,
                              void* d_out, int out_size, void* d_ws, size_t ws_size,
                              hipStream_t stream)
{
  const float* seq  = (const float*)d_in[0];
  const void*  ei   = d_in[1];
  const float* Wihf = (const float*)d_in[2];
  const float* Whhf = (const float*)d_in[3];
  const float* bih  = (const float*)d_in[4];
  const float* bhh  = (const float*)d_in[5];
  const float* linw = (const float*)d_in[6];
  const float* atts = (const float*)d_in[7];
  const float* attd = (const float*)d_in[8];
  const float* gbias= (const float*)d_in[9];

  const int N  = in_sizes[0] / (16*128);
  const int E  = in_sizes[1] / 2;
  const int nT = (N + 15) / 16;
  const int nB = (N + 1023) / 1024;

  char* ws = (char*)d_ws;
  size_t off_b = 0;
  auto alloc = [&](size_t bytes) -> char* {
    char* p = ws + off_b;
    off_b = (off_b + bytes + 255) & ~(size_t)255;
    return p;
  };
  unsigned short* Wih_sw = (unsigned short*)alloc(98304);
  unsigned short* Whh_sw = (unsigned short*)alloc(98304);
  unsigned short* lin_sw = (unsigned short*)alloc(32768);
  unsigned short* xbf    = (unsigned short*)alloc((size_t)N*128*2);
  float*    a_s    = (float*)   alloc((size_t)N*4);
  float*    a_d    = (float*)   alloc((size_t)N*4);
  unsigned* flag   = (unsigned*)alloc(64);
  int*      srcA   = (int*)     alloc((size_t)E*4);
  int*      dstA   = (int*)     alloc((size_t)E*4);
  int*      deg    = (int*)     alloc((size_t)N*4);
  int*      offs   = (int*)     alloc((size_t)(N+1)*4);
  int*      cur    = (int*)     alloc((size_t)N*4);
  int*      eid    = (int*)     alloc((size_t)E*4);
  int*      bsum   = (int*)     alloc((size_t)(nB+1)*4);
  int*      total  = (int*)     alloc(64);

  float* hout = (float*)d_out;
  float* out2 = hout + (size_t)N*128;

  k_prep   <<<448, 256, 0, stream>>>(Wihf, Whhf, linw, Wih_sw, Whh_sw, lin_sw);
  k_detect <<<1, 64, 0, stream>>>((const int*)ei, flag);
  k_zero   <<<(N + 255)/256, 256, 0, stream>>>(deg, N);
  k_norm   <<<(E + 255)/256, 256, 0, stream>>>(ei, flag, srcA, dstA, deg, E);
  k_scanA  <<<nB, 256, 0, stream>>>(deg, offs, bsum, N);
  k_scanB  <<<1, 64, 0, stream>>>(bsum, total, nB);
  k_scanC  <<<(N + 255)/256, 256, 0, stream>>>(offs, bsum, total, cur, N);
  k_scatter<<<(E + 255)/256, 256, 0, stream>>>(srcA, dstA, offs, cur, eid, E);

  k_gru_fused<<<nT, 512, 0, stream>>>(Wih_sw, Whh_sw, bih, bhh, seq, hout, nT, N);

  k_gat1<<<(nT + 3)/4, 256, 0, stream>>>(hout, lin_sw, atts, attd, xbf, a_s, a_d, N, nT);
  k_agg2<<<(N + 3)/4, 256, 0, stream>>>(offs, eid, a_s, a_d, xbf, gbias, out2, N);
}

// Round 10
// 229.806 us; speedup vs baseline: 5.3065x; 1.2153x over previous
//
#include <hip/hip_runtime.h>

typedef __bf16 bf16x8 __attribute__((ext_vector_type(8)));
typedef float  f32x4  __attribute__((ext_vector_type(4)));
union BF8 { unsigned short s[8]; bf16x8 v; };

__device__ __forceinline__ unsigned short f2bf(float x){
  unsigned u = __float_as_uint(x);
  u += 0x7fffu + ((u >> 16) & 1u);      // round-to-nearest-even
  return (unsigned short)(u >> 16);
}
__device__ __forceinline__ unsigned cvt_pk_bf16(float lo, float hi){
  unsigned r;
  asm("v_cvt_pk_bf16_f32 %0, %1, %2" : "=v"(r) : "v"(lo), "v"(hi));
  return r;
}
__device__ __forceinline__ float bf2f(unsigned short s){ return __uint_as_float(((unsigned)s) << 16); }
__device__ __forceinline__ float sigm(float x){ return 1.0f/(1.0f + __expf(-x)); }
__device__ __forceinline__ float tanh_fast(float x){ return 1.0f - 2.0f/(__expf(2.0f*x)+1.0f); }

// ---------------- prep: W -> bf16 pre-swizzled (chunk-of-8 ^ (row&7)) ----------------
__global__ void k_prep(const float* __restrict__ Wihf, const float* __restrict__ Whhf,
                       const float* __restrict__ linw,
                       unsigned short* __restrict__ Wih_sw, unsigned short* __restrict__ Whh_sw,
                       unsigned short* __restrict__ lin_sw)
{
  int tid = blockIdx.x*256 + threadIdx.x;
  if (tid < 49152){
    int row = tid >> 7, col = tid & 127;
    Wih_sw[row*128 + (((col>>3) ^ (row&7))<<3) + (col&7)] = f2bf(Wihf[tid]);
  } else if (tid < 98304){
    int i = tid - 49152; int row = i >> 7, col = i & 127;
    Whh_sw[row*128 + (((col>>3) ^ (row&7))<<3) + (col&7)] = f2bf(Whhf[i]);
  } else if (tid < 114688){
    int i = tid - 98304; int row = i >> 7, col = i & 127;
    lin_sw[row*128 + (((col>>3) ^ (row&7))<<3) + (col&7)] = f2bf(linw[i]);
  }
}

// ---------------- edge index dtype sniff ----------------
__global__ void k_detect(const int* __restrict__ ei, unsigned* __restrict__ flag){
  int v = ei[2*threadIdx.x + 1];
  unsigned long long b = __ballot(v == 0);
  if (threadIdx.x == 0) flag[0] = (b == ~0ULL) ? 1u : 0u;
}

__global__ void k_zero(int* __restrict__ deg, int N){
  int tid = blockIdx.x*256 + threadIdx.x;
  if (tid < N) deg[tid] = 0;
}

__global__ void k_norm(const void* __restrict__ ei, const unsigned* __restrict__ flag,
                       int* __restrict__ src, int* __restrict__ dst, int* __restrict__ deg, int E){
  int e = blockIdx.x*256 + threadIdx.x;
  if (e >= E) return;
  int s, d;
  if (flag[0]){
    const long long* p = (const long long*)ei;
    s = (int)p[e]; d = (int)p[(size_t)E + e];
  } else {
    const int* p = (const int*)ei;
    s = p[e]; d = p[E + e];
  }
  src[e] = s; dst[e] = d;
  atomicAdd(&deg[d], 1);
}

// ---------------- parallel 3-level exclusive scan of deg -> off ----------------
__global__ __launch_bounds__(256) void k_scanA(const int* __restrict__ deg,
    int* __restrict__ off, int* __restrict__ bsum, int N){
  __shared__ int wsum[4];
  const int b = blockIdx.x, t = threadIdx.x;
  const int lane = t & 63, wv = t >> 6;
  const int base = b*1024 + t*4;
  int v[4]; int s = 0;
  #pragma unroll
  for (int j=0;j<4;++j){ v[j] = (base+j < N) ? deg[base+j] : 0; s += v[j]; }
  int inc = s;
  #pragma unroll
  for (int d2=1; d2<64; d2<<=1){ int u = __shfl_up(inc, d2); if (lane >= d2) inc += u; }
  if (lane == 63) wsum[wv] = inc;
  __syncthreads();
  int woff = 0;
  #pragma unroll
  for (int j=0;j<4;++j) if (j < wv) woff += wsum[j];
  int ex = woff + inc - s;
  #pragma unroll
  for (int j=0;j<4;++j){
    if (base+j < N) off[base+j] = ex;
    ex += v[j];
  }
  if (t == 255) bsum[b] = woff + inc;
}

__global__ void k_scanB(int* __restrict__ bsum, int* __restrict__ total, int nB){
  int lane = threadIdx.x;
  int carry = 0;
  for (int base = 0; base < nB; base += 64){
    int i = base + lane;
    int v = (i < nB) ? bsum[i] : 0;
    int inc = v;
    #pragma unroll
    for (int d2=1; d2<64; d2<<=1){ int u = __shfl_up(inc, d2); if (lane >= d2) inc += u; }
    if (i < nB) bsum[i] = carry + inc - v;
    carry += __shfl(inc, 63);
  }
  if (lane == 0) total[0] = carry;
}

__global__ void k_scanC(int* __restrict__ off, const int* __restrict__ bsum,
    const int* __restrict__ total, int* __restrict__ cur, int N){
  int i = blockIdx.x*256 + threadIdx.x;
  if (i < N){ off[i] += bsum[i>>10]; cur[i] = 0; }
  if (i == 0) off[N] = total[0];
}

__global__ void k_scatter(const int* __restrict__ src, const int* __restrict__ dst,
                          const int* __restrict__ off, int* __restrict__ cur,
                          int* __restrict__ eid, int E){
  int e = blockIdx.x*256 + threadIdx.x;
  if (e >= E) return;
  int d = dst[e];
  int p = off[d] + atomicAdd(&cur[d], 1);
  eid[p] = src[e];
}

// ---------------- fused GRU: weights in registers, channel-split, x-part pipelined -----
__global__ __launch_bounds__(512, 2) void k_gru_fused(
    const unsigned short* __restrict__ Wih_sw, const unsigned short* __restrict__ Whh_sw,
    const float* __restrict__ bih, const float* __restrict__ bhh,
    const float* __restrict__ seq, float* __restrict__ hout, int nT, int N)
{
  __shared__ unsigned short xbuf[2][16*256];   // [buf][node][s(2 steps)][ch swz]
  __shared__ unsigned short hbuf[2][16*128];   // [buf][node][ch swz]
  const int tid  = threadIdx.x;
  const int lane = tid & 63, w = tid >> 6;     // w = channel chunk 0..7
  const int col4 = lane & 15, grp = lane >> 4;
  const int tile = blockIdx.x;
  const int ch   = 16*w + col4;                // this lane's output channel

  bf16x8 Wf[6][4];
  #pragma unroll
  for (int s6=0; s6<6; ++s6){
    const unsigned short* Wp = (s6 < 3) ? Wih_sw : Whh_sw;
    int row = (s6 % 3)*128 + ch;
    #pragma unroll
    for (int kt=0; kt<4; ++kt)
      Wf[s6][kt] = *(const bf16x8*)(Wp + row*128 + (((kt*4+grp) ^ (row&7))<<3));
  }
  const float brz_r = bih[ch]       + bhh[ch];
  const float brz_z = bih[128 + ch] + bhh[128 + ch];
  const float b_xn  = bih[256 + ch];
  const float b_hn  = bhh[256 + ch];

  float hreg[4] = {0.f, 0.f, 0.f, 0.f};

  f32x4 sv[2];
  auto stageIssue = [&](int tp){
    #pragma unroll
    for (int rr=0; rr<2; ++rr){
      int nrow = tile*16 + 2*w + rr; if (nrow >= N) nrow = N-1;
      sv[rr] = *(const f32x4*)(seq + ((size_t)nrow*16 + tp)*128 + lane*4);
    }
  };
  auto stageWrite = [&](int buf){
    const int s  = lane >> 5;
    const int c0 = (lane & 31) * 4;
    #pragma unroll
    for (int rr=0; rr<2; ++rr){
      int node = 2*w + rr;
      int chunk = (c0 >> 3) ^ node;
      uint2 pk;
      pk.x = cvt_pk_bf16(sv[rr][0], sv[rr][1]);
      pk.y = cvt_pk_bf16(sv[rr][2], sv[rr][3]);
      *(uint2*)(&xbuf[buf][node*256 + s*128 + chunk*8 + (c0 & 7)]) = pk;
    }
  };
  auto staging = [&](int t){                  // call at even t only
    int pw = t/2 + 1;
    if (pw <= 7) stageWrite(pw & 1);
    int pi = t/2 + 2;
    if (pi <= 7) stageIssue(pi*2);
  };

  // x-part: accNext = bias + x(t1) @ Wih
  auto xPart = [&](int t1, f32x4& nr, f32x4& nz, f32x4& nn){
    bf16x8 xa[4];
    const unsigned short* xb = xbuf[(t1>>1)&1] + col4*256 + (t1&1)*128;
    #pragma unroll
    for (int kt=0;kt<4;++kt){
      int chunk = (kt*4+grp) ^ col4;
      xa[kt] = *(const bf16x8*)(xb + chunk*8);
    }
    nr = (f32x4){brz_r, brz_r, brz_r, brz_r};
    nz = (f32x4){brz_z, brz_z, brz_z, brz_z};
    nn = (f32x4){b_xn,  b_xn,  b_xn,  b_xn };
    #pragma unroll
    for (int kt=0; kt<4; ++kt){
      nr = __builtin_amdgcn_mfma_f32_16x16x32_bf16(xa[kt], Wf[0][kt], nr, 0,0,0);
      nz = __builtin_amdgcn_mfma_f32_16x16x32_bf16(xa[kt], Wf[1][kt], nz, 0,0,0);
      nn = __builtin_amdgcn_mfma_f32_16x16x32_bf16(xa[kt], Wf[2][kt], nn, 0,0,0);
    }
  };
  // h-part: cr,cz += h(t-1)@Whh ; chn = b_hn + h(t-1)@Whh_n
  auto hPart = [&](int t, f32x4& cr, f32x4& cz, f32x4& chn){
    bf16x8 ha[4];
    const unsigned short* hb = hbuf[t&1];
    #pragma unroll
    for (int kt=0;kt<4;++kt){
      int chunk = (kt*4+grp) ^ col4;
      ha[kt] = *(const bf16x8*)(hb + col4*128 + chunk*8);
    }
    chn = (f32x4){b_hn, b_hn, b_hn, b_hn};
    #pragma unroll
    for (int kt=0; kt<4; ++kt){
      cr  = __builtin_amdgcn_mfma_f32_16x16x32_bf16(ha[kt], Wf[3][kt], cr , 0,0,0);
      cz  = __builtin_amdgcn_mfma_f32_16x16x32_bf16(ha[kt], Wf[4][kt], cz , 0,0,0);
      chn = __builtin_amdgcn_mfma_f32_16x16x32_bf16(ha[kt], Wf[5][kt], chn, 0,0,0);
    }
  };
  auto gates = [&](int t, const f32x4& cr, const f32x4& cz, const f32x4& cn, const f32x4& chn){
    unsigned short* hbw = hbuf[(t+1)&1];
    #pragma unroll
    for (int q=0; q<4; q+=2){
      float r0 = sigm(cr[q]),   z0 = sigm(cz[q]);
      float n0 = tanh_fast(cn[q]   + r0*chn[q]);
      float h0 = n0 + z0*(hreg[q]   - n0); hreg[q]   = h0;
      float r1 = sigm(cr[q+1]), z1 = sigm(cz[q+1]);
      float n1 = tanh_fast(cn[q+1] + r1*chn[q+1]);
      float h1 = n1 + z1*(hreg[q+1] - n1); hreg[q+1] = h1;
      if (t < 15){
        unsigned pk = cvt_pk_bf16(h0, h1);
        int nd0 = grp*4 + q, nd1 = nd0 + 1;
        int c0 = ((ch>>3) ^ nd0), c1 = ((ch>>3) ^ nd1);
        hbw[nd0*128 + c0*8 + (ch&7)] = (unsigned short)pk;
        hbw[nd1*128 + c1*8 + (ch&7)] = (unsigned short)(pk >> 16);
      }
    }
  };

  // prologue
  stageIssue(0); stageWrite(0);
  stageIssue(2);
  __syncthreads();

  f32x4 Ar, Az, An, Br, Bz, Bn, Hn;
  xPart(0, Ar, Az, An);
  Hn = (f32x4){b_hn, b_hn, b_hn, b_hn};      // h(-1) = 0
  gates(0, Ar, Az, An, Hn);
  staging(0);
  xPart(1, Br, Bz, Bn);

  for (int tp = 0; tp < 7; ++tp){
    const int t1 = 2*tp + 1, t2 = 2*tp + 2;
    __syncthreads();
    hPart(t1, Br, Bz, Hn);
    gates(t1, Br, Bz, Bn, Hn);
    xPart(t2, Ar, Az, An);
    __syncthreads();
    hPart(t2, Ar, Az, Hn);
    gates(t2, Ar, Az, An, Hn);
    staging(t2);
    xPart(t2 + 1, Br, Bz, Bn);
  }
  __syncthreads();
  hPart(15, Br, Bz, Hn);
  gates(15, Br, Bz, Bn, Hn);

  #pragma unroll
  for (int q=0; q<4; ++q){
    int n = tile*16 + grp*4 + q;
    if (n < N) hout[(size_t)n*128 + ch] = hreg[q];
  }
}

// ---------------- GAT linear (MFMA) + fused attention scalars; x stored bf16 ----------------
__global__ __launch_bounds__(256) void k_gat1(
    const float* __restrict__ hsrc, const unsigned short* __restrict__ lin_sw,
    const float* __restrict__ att_s, const float* __restrict__ att_d,
    unsigned short* __restrict__ xbf, float* __restrict__ a_s, float* __restrict__ a_d,
    int N, int nT)
{
  __shared__ unsigned short Llds[16384];
  const int tid = threadIdx.x;
  for (int i = tid; i < 2048; i += 256)
    ((uint4*)Llds)[i] = ((const uint4*)lin_sw)[i];
  __syncthreads();
  const int lane = tid & 63, wloc = tid >> 6;
  const int col4 = lane & 15, grp = lane >> 4;
  const int tile = blockIdx.x*4 + wloc;
  if (tile >= nT) return;
  float ats[8], atd[8];
  #pragma unroll
  for (int ct=0;ct<8;++ct){ ats[ct] = att_s[ct*16+col4]; atd[ct] = att_d[ct*16+col4]; }
  int nrow = tile*16 + col4; if (nrow >= N) nrow = N-1;
  const float* xr = hsrc + (size_t)nrow*128 + grp*8;
  bf16x8 xa[4];
  #pragma unroll
  for (int kt=0;kt<4;++kt){
    f32x4 lo = *(const f32x4*)(xr + kt*32);
    f32x4 hi = *(const f32x4*)(xr + kt*32 + 4);
    BF8 u;
    #pragma unroll
    for (int j=0;j<4;++j){ u.s[j]=f2bf(lo[j]); u.s[4+j]=f2bf(hi[j]); }
    xa[kt] = u.v;
  }
  f32x4 acc[8];
  #pragma unroll
  for (int ct=0;ct<8;++ct) acc[ct] = (f32x4)0.0f;
  #pragma unroll
  for (int kt=0;kt<4;++kt){
    #pragma unroll
    for (int ct=0;ct<8;++ct){
      int row = ct*16+col4;
      const bf16x8 b = *(const bf16x8*)(Llds + row*128 + (((kt*4+grp)^(row&7))<<3));
      acc[ct] = __builtin_amdgcn_mfma_f32_16x16x32_bf16(xa[kt], b, acc[ct], 0,0,0);
    }
  }
  float ss[4] = {0,0,0,0}, dd[4] = {0,0,0,0};
  #pragma unroll
  for (int ct=0;ct<8;++ct)
    #pragma unroll
    for (int q=0;q<4;++q){
      float xv = acc[ct][q];
      int n = tile*16 + grp*4 + q;
      if (n < N) xbf[(size_t)n*128 + ct*16 + col4] = f2bf(xv);
      ss[q] += xv * ats[ct];
      dd[q] += xv * atd[ct];
    }
  #pragma unroll
  for (int m=1; m<16; m<<=1){
    #pragma unroll
    for (int q=0;q<4;++q){
      ss[q] += __shfl_xor(ss[q], m);
      dd[q] += __shfl_xor(dd[q], m);
    }
  }
  if (col4 == 0){
    #pragma unroll
    for (int q=0;q<4;++q){
      int n = tile*16 + grp*4 + q;
      if (n < N){ a_s[n] = ss[q]; a_d[n] = dd[q]; }
    }
  }
}

// ---------------- CSR aggregation: one wave per destination node, 4x unrolled ----------------
__global__ __launch_bounds__(256) void k_agg2(
    const int* __restrict__ off, const int* __restrict__ eid,
    const float* __restrict__ a_s, const float* __restrict__ a_d,
    const unsigned short* __restrict__ xbf, const float* __restrict__ bias,
    float* __restrict__ out2, int N)
{
  int d = blockIdx.x*4 + (threadIdx.x >> 6);
  if (d >= N) return;
  const int lane = threadIdx.x & 63;
  const unsigned* xw = (const unsigned*)xbf;   // 2 bf16 channels per uint
  const float ad_d = a_d[d];
  float a0 = a_s[d] + ad_d; a0 = a0 > 0.f ? a0 : 0.2f*a0;
  float w = __expf(a0);
  unsigned pv = xw[(size_t)d*64 + lane];
  float den  = w;
  float acc0 = w * bf2f((unsigned short)(pv & 0xffffu));
  float acc1 = w * bf2f((unsigned short)(pv >> 16));
  int i = off[d];
  const int i1 = off[d+1];
  for (; i + 3 < i1; i += 4){
    int s0 = eid[i], s1 = eid[i+1], s2 = eid[i+2], s3 = eid[i+3];
    unsigned p0 = xw[(size_t)s0*64 + lane];
    unsigned p1 = xw[(size_t)s1*64 + lane];
    unsigned p2 = xw[(size_t)s2*64 + lane];
    unsigned p3 = xw[(size_t)s3*64 + lane];
    float b0 = a_s[s0] + ad_d, b1 = a_s[s1] + ad_d, b2 = a_s[s2] + ad_d, b3 = a_s[s3] + ad_d;
    b0 = b0 > 0.f ? b0 : 0.2f*b0;  b1 = b1 > 0.f ? b1 : 0.2f*b1;
    b2 = b2 > 0.f ? b2 : 0.2f*b2;  b3 = b3 > 0.f ? b3 : 0.2f*b3;
    float w0 = __expf(b0), w1 = __expf(b1), w2 = __expf(b2), w3 = __expf(b3);
    den += w0 + w1 + w2 + w3;
    acc0 += w0 * bf2f((unsigned short)(p0 & 0xffffu)) + w1 * bf2f((unsigned short)(p1 & 0xffffu))
          + w2 * bf2f((unsigned short)(p2 & 0xffffu)) + w3 * bf2f((unsigned short)(p3 & 0xffffu));
    acc1 += w0 * bf2f((unsigned short)(p0 >> 16)) + w1 * bf2f((unsigned short)(p1 >> 16))
          + w2 * bf2f((unsigned short)(p2 >> 16)) + w3 * bf2f((unsigned short)(p3 >> 16));
  }
  for (; i < i1; ++i){
    int s = eid[i];
    float a = a_s[s] + ad_d; a = a > 0.f ? a : 0.2f*a;
    float ww = __expf(a);
    unsigned pp = xw[(size_t)s*64 + lane];
    den  += ww;
    acc0 += ww * bf2f((unsigned short)(pp & 0xffffu));
    acc1 += ww * bf2f((unsigned short)(pp >> 16));
  }
  float inv = 1.0f/den;
  float2 o;
  o.x = acc0*inv + bias[2*lane];
  o.y = acc1*inv + bias[2*lane+1];
  *(float2*)(out2 + (size_t)d*128 + 2*lane) = o;
}

extern "C" void kernel_launch(void* const* d_in, const int* in_sizes, int n_in,
                              void* d_out, int out_size, void* d_ws, size_t ws_size,
                              hipStream_t stream)
{
  const float* seq  = (const float*)d_in[0];
  const void*  ei   = d_in[1];
  const float* Wihf = (const float*)d_in[2];
  const float* Whhf = (const float*)d_in[3];
  const float* bih  = (const float*)d_in[4];
  const float* bhh  = (const float*)d_in[5];
  const float* linw = (const float*)d_in[6];
  const float* atts = (const float*)d_in[7];
  const float* attd = (const float*)d_in[8];
  const float* gbias= (const float*)d_in[9];

  const int N  = in_sizes[0] / (16*128);
  const int E  = in_sizes[1] / 2;
  const int nT = (N + 15) / 16;
  const int nB = (N + 1023) / 1024;

  char* ws = (char*)d_ws;
  size_t off_b = 0;
  auto alloc = [&](size_t bytes) -> char* {
    char* p = ws + off_b;
    off_b = (off_b + bytes + 255) & ~(size_t)255;
    return p;
  };
  unsigned short* Wih_sw = (unsigned short*)alloc(98304);
  unsigned short* Whh_sw = (unsigned short*)alloc(98304);
  unsigned short* lin_sw = (unsigned short*)alloc(32768);
  unsigned short* xbf    = (unsigned short*)alloc((size_t)N*128*2);
  float*    a_s    = (float*)   alloc((size_t)N*4);
  float*    a_d    = (float*)   alloc((size_t)N*4);
  unsigned* flag   = (unsigned*)alloc(64);
  int*      srcA   = (int*)     alloc((size_t)E*4);
  int*      dstA   = (int*)     alloc((size_t)E*4);
  int*      deg    = (int*)     alloc((size_t)N*4);
  int*      offs   = (int*)     alloc((size_t)(N+1)*4);
  int*      cur    = (int*)     alloc((size_t)N*4);
  int*      eid    = (int*)     alloc((size_t)E*4);
  int*      bsum   = (int*)     alloc((size_t)(nB+1)*4);
  int*      total  = (int*)     alloc(64);

  float* hout = (float*)d_out;
  float* out2 = hout + (size_t)N*128;

  k_prep   <<<448, 256, 0, stream>>>(Wihf, Whhf, linw, Wih_sw, Whh_sw, lin_sw);
  k_detect <<<1, 64, 0, stream>>>((const int*)ei, flag);
  k_zero   <<<(N + 255)/256, 256, 0, stream>>>(deg, N);
  k_norm   <<<(E + 255)/256, 256, 0, stream>>>(ei, flag, srcA, dstA, deg, E);
  k_scanA  <<<nB, 256, 0, stream>>>(deg, offs, bsum, N);
  k_scanB  <<<1, 64, 0, stream>>>(bsum, total, nB);
  k_scanC  <<<(N + 255)/256, 256, 0, stream>>>(offs, bsum, total, cur, N);
  k_scatter<<<(E + 255)/256, 256, 0, stream>>>(srcA, dstA, offs, cur, eid, E);

  k_gru_fused<<<nT, 512, 0, stream>>>(Wih_sw, Whh_sw, bih, bhh, seq, hout, nT, N);

  k_gat1<<<(nT + 3)/4, 256, 0, stream>>>(hout, lin_sw, atts, attd, xbf, a_s, a_d, N, nT);
  k_agg2<<<(N + 3)/4, 256, 0, stream>>>(offs, eid, a_s, a_d, xbf, gbias, out2, N);
}